// Round 1
// baseline (1263.526 us; speedup 1.0000x reference)
//
#include <hip/hip_runtime.h>
#include <math.h>

#define C_N   2000
#define DIMN  128
#define DM    256
#define B_N   8
#define HT    16
#define S_N   64
#define NSEQ  136
#define DFF   1024
#define NEDGE (B_N*HT*(S_N-1))   // 8064

// ---------------- graph / GCN ----------------

__global__ void k_colsum(const int* __restrict__ hist, float* __restrict__ colsum) {
    int e = blockIdx.x * blockDim.x + threadIdx.x;
    if (e >= NEDGE) return;
    int s = e % (S_N-1); int bh = e / (S_N-1); int h = bh % HT; int b = bh / HT;
    const int* row = hist + (size_t)bh * S_N;
    int src = row[s], dst = row[s+1];
    if (src != C_N && dst != C_N && src != dst) {
        float w = 1.f + expf(-0.01f * (float)(HT - 1 - h));
        atomicAdd(&colsum[b * C_N + dst], w);
    }
}

__global__ void k_dsqrt(float* __restrict__ dv) {
    int i = blockIdx.x * blockDim.x + threadIdx.x;
    if (i < B_N * C_N) dv[i] = sqrtf(1.f + dv[i]);
}

__global__ void k_initX(const float* __restrict__ dv, const float* __restrict__ E,
                        float* __restrict__ X) {
    size_t i = (size_t)blockIdx.x * 256 + threadIdx.x;   // over B*C*DIM
    int k = (int)(i % DIMN); size_t bc = i / DIMN;
    int c = (int)(bc % C_N); int b = (int)(bc / C_N);
    float dd = dv[b * C_N + c];
    X[i] = dd * dd * E[(size_t)c * DIMN + k];
}

__global__ void k_edgeX(const int* __restrict__ hist, const float* __restrict__ dv,
                        const float* __restrict__ E, float* __restrict__ X) {
    int e = blockIdx.x;
    int s = e % (S_N-1); int bh = e / (S_N-1); int h = bh % HT; int b = bh / HT;
    const int* row = hist + (size_t)bh * S_N;
    int src = row[s], dst = row[s+1];
    if (src == C_N || dst == C_N || src == dst) return;
    float w = (1.f + expf(-0.01f * (float)(HT - 1 - h))) * dv[b*C_N+src] * dv[b*C_N+dst];
    int k = threadIdx.x;  // 128
    atomicAdd(&X[((size_t)b * C_N + src) * DIMN + k], w * E[(size_t)dst * DIMN + k]);
}

// ---------------- generic tiled GEMM ----------------
// C[M,N] = epi(A[M,K] @ B[K,N] (+bias) (+resid)), B optionally stored (N,K) (BTRANS)
// EPI bits: 1=bias, 2=relu, 4=residual
template<int EPI, bool BTRANS>
__global__ __launch_bounds__(256) void k_gemm(
        const float* __restrict__ A, const float* __restrict__ Bm,
        const float* __restrict__ bias, const float* __restrict__ resid,
        float* __restrict__ Cm, int M, int N, int K)
{
    __shared__ float As[16][65];
    __shared__ float Bs[16][65];
    int tid = threadIdx.x;
    int tx = tid & 15, ty = tid >> 4;
    int m0 = blockIdx.y * 64, n0 = blockIdx.x * 64;
    float acc[4][4] = {};
    for (int k0 = 0; k0 < K; k0 += 16) {
        { // A tile: 64 rows x 16 k
            int mm = tid >> 2;
            int kk = (tid & 3) << 2;
            int m = m0 + mm;
            float4 v = {0,0,0,0};
            if (m < M) v = *(const float4*)(A + (size_t)m * K + k0 + kk);
            As[kk+0][mm] = v.x; As[kk+1][mm] = v.y; As[kk+2][mm] = v.z; As[kk+3][mm] = v.w;
        }
        if (!BTRANS) { // B tile: 16 k x 64 n
            int kk = tid >> 4;
            int nn = (tid & 15) << 2;
            int n = n0 + nn;
            const float* src = Bm + (size_t)(k0+kk) * N + n;
            float4 v = {0,0,0,0};
            if (n + 3 < N) v = *(const float4*)src;
            else {
                if (n   < N) v.x = src[0];
                if (n+1 < N) v.y = src[1];
                if (n+2 < N) v.z = src[2];
                if (n+3 < N) v.w = src[3];
            }
            Bs[kk][nn] = v.x; Bs[kk][nn+1] = v.y; Bs[kk][nn+2] = v.z; Bs[kk][nn+3] = v.w;
        } else {      // B stored (N,K)
            int nn = tid >> 2;
            int kk = (tid & 3) << 2;
            int n = n0 + nn;
            float4 v = {0,0,0,0};
            if (n < N) v = *(const float4*)(Bm + (size_t)n * K + k0 + kk);
            Bs[kk+0][nn] = v.x; Bs[kk+1][nn] = v.y; Bs[kk+2][nn] = v.z; Bs[kk+3][nn] = v.w;
        }
        __syncthreads();
        #pragma unroll
        for (int kk = 0; kk < 16; ++kk) {
            float a[4], b[4];
            #pragma unroll
            for (int i = 0; i < 4; ++i) a[i] = As[kk][ty*4+i];
            #pragma unroll
            for (int j = 0; j < 4; ++j) b[j] = Bs[kk][tx*4+j];
            #pragma unroll
            for (int i = 0; i < 4; ++i)
                #pragma unroll
                for (int j = 0; j < 4; ++j)
                    acc[i][j] = fmaf(a[i], b[j], acc[i][j]);
        }
        __syncthreads();
    }
    #pragma unroll
    for (int i = 0; i < 4; ++i) {
        int m = m0 + ty*4 + i;
        if (m >= M) continue;
        #pragma unroll
        for (int j = 0; j < 4; ++j) {
            int n = n0 + tx*4 + j;
            if (n >= N) continue;
            float v = acc[i][j];
            if (EPI & 1) v += bias[n];
            if (EPI & 4) v += resid[(size_t)m * N + n];
            if (EPI & 2) v = fmaxf(v, 0.f);
            Cm[(size_t)m * N + n] = v;
        }
    }
}

// ---------------- temporal encoding + fuse ----------------

__global__ void k_temp(float* __restrict__ temp) {
    int s = blockIdx.x; int d = threadIdx.x;
    int k = d >> 1;
    float den = powf(10000.f, (2.f * (float)k) / 256.f);
    float arg = (float)s / den;
    temp[s * DM + d] = (d & 1) ? cosf(arg) : sinf(arg);
}

__global__ void k_fuse(const int* __restrict__ hist, const int* __restrict__ cur,
                       const float* __restrict__ E, const float* __restrict__ Eg,
                       const float* __restrict__ nullE, const float* __restrict__ temp,
                       float* __restrict__ Xenc, float* __restrict__ maskb) {
    int blk = blockIdx.x;           // seq*64 + s
    int seq = blk >> 6, s = blk & 63;
    int d = threadIdx.x;
    int idx, b;
    if (seq < 128) { b = seq >> 4; idx = hist[(size_t)seq * S_N + s]; }
    else           { b = seq - 128; idx = cur[b * S_N + s]; }
    float t = temp[s * DM + d];
    float v;
    if (idx == C_N) v = nullE[d] + t;
    else {
        v = ((d < DIMN) ? E[(size_t)idx * DIMN + d]
                        : Eg[((size_t)b * C_N + idx) * DIMN + (d - DIMN)]) + t;
    }
    Xenc[((size_t)seq * S_N + s) * DM + d] = v;
    if (d == 0) maskb[seq * S_N + s] = (idx == C_N) ? -INFINITY : 0.f;
}

// ---------------- attention (encoder: key-padding mask) ----------------

__global__ __launch_bounds__(256) void k_attn(
        const float* __restrict__ Q, const float* __restrict__ K,
        const float* __restrict__ V, const float* __restrict__ maskb,
        float* __restrict__ O) {
    int seq = blockIdx.x >> 2, head = blockIdx.x & 3;
    __shared__ float Qs[64][65], Ks[64][65], Vs[64][65];
    __shared__ float mk[64];
    int tid = threadIdx.x;
    int d = tid & 63;
    #pragma unroll
    for (int i = 0; i < 16; ++i) {
        int s = (tid >> 6) + i * 4;
        size_t base = ((size_t)seq * S_N + s) * DM + head * 64 + d;
        Qs[s][d] = Q[base]; Ks[s][d] = K[base]; Vs[s][d] = V[base];
    }
    if (tid < 64) mk[tid] = maskb[seq * S_N + tid];
    __syncthreads();
    int r = tid >> 2, q4 = tid & 3;
    float sc[16];
    #pragma unroll
    for (int j = 0; j < 16; ++j) {
        int c = q4 + j * 4;
        float s = 0.f;
        #pragma unroll 8
        for (int dd = 0; dd < 64; ++dd) s = fmaf(Qs[r][dd], Ks[c][dd], s);
        sc[j] = s * 0.125f + mk[c];
    }
    float mx = sc[0];
    #pragma unroll
    for (int j = 1; j < 16; ++j) mx = fmaxf(mx, sc[j]);
    mx = fmaxf(mx, __shfl_xor(mx, 1));
    mx = fmaxf(mx, __shfl_xor(mx, 2));
    float sum = 0.f;
    #pragma unroll
    for (int j = 0; j < 16; ++j) { sc[j] = expf(sc[j] - mx); sum += sc[j]; }
    sum += __shfl_xor(sum, 1);
    sum += __shfl_xor(sum, 2);
    float inv = 1.f / sum;
    __syncthreads();
    #pragma unroll
    for (int j = 0; j < 16; ++j) Qs[r][q4 + j * 4] = sc[j] * inv;  // P into Qs
    __syncthreads();
    float outv[16];
    #pragma unroll
    for (int j = 0; j < 16; ++j) {
        int dd = q4 + j * 4;
        float s = 0.f;
        #pragma unroll 8
        for (int c = 0; c < 64; ++c) s = fmaf(Qs[r][c], Vs[c][dd], s);
        outv[j] = s;
    }
    #pragma unroll
    for (int j = 0; j < 16; ++j) {
        int dd = q4 + j * 4;
        O[((size_t)seq * S_N + r) * DM + head * 64 + dd] = outv[j];
    }
}

// ---------------- attention (WCA: window mask, kv from mc per batch) ----------------

__global__ __launch_bounds__(256) void k_attn_wca(
        const float* __restrict__ Q, const float* __restrict__ Kc,
        const float* __restrict__ Vc, float* __restrict__ O) {
    int seq = blockIdx.x >> 2, head = blockIdx.x & 3;
    int b = seq >> 4;
    __shared__ float Qs[64][65], Ks[64][65], Vs[64][65];
    int tid = threadIdx.x;
    int d = tid & 63;
    #pragma unroll
    for (int i = 0; i < 16; ++i) {
        int s = (tid >> 6) + i * 4;
        Qs[s][d] = Q[((size_t)seq * S_N + s) * DM + head * 64 + d];
        size_t kb = ((size_t)b * S_N + s) * DM + head * 64 + d;
        Ks[s][d] = Kc[kb]; Vs[s][d] = Vc[kb];
    }
    __syncthreads();
    int r = tid >> 2, q4 = tid & 3;
    float sc[16];
    #pragma unroll
    for (int j = 0; j < 16; ++j) {
        int c = q4 + j * 4;
        if (abs(r - c) <= 4) {
            float s = 0.f;
            #pragma unroll 8
            for (int dd = 0; dd < 64; ++dd) s = fmaf(Qs[r][dd], Ks[c][dd], s);
            sc[j] = s * 0.125f;
        } else sc[j] = -INFINITY;
    }
    float mx = sc[0];
    #pragma unroll
    for (int j = 1; j < 16; ++j) mx = fmaxf(mx, sc[j]);
    mx = fmaxf(mx, __shfl_xor(mx, 1));
    mx = fmaxf(mx, __shfl_xor(mx, 2));
    float sum = 0.f;
    #pragma unroll
    for (int j = 0; j < 16; ++j) { sc[j] = expf(sc[j] - mx); sum += sc[j]; }
    sum += __shfl_xor(sum, 1);
    sum += __shfl_xor(sum, 2);
    float inv = 1.f / sum;
    __syncthreads();
    #pragma unroll
    for (int j = 0; j < 16; ++j) Qs[r][q4 + j * 4] = sc[j] * inv;
    __syncthreads();
    float outv[16];
    #pragma unroll
    for (int j = 0; j < 16; ++j) {
        int dd = q4 + j * 4;
        float s = 0.f;
        #pragma unroll 8
        for (int c = 0; c < 64; ++c) s = fmaf(Qs[r][c], Vs[c][dd], s);
        outv[j] = s;
    }
    #pragma unroll
    for (int j = 0; j < 16; ++j) {
        int dd = q4 + j * 4;
        O[((size_t)seq * S_N + r) * DM + head * 64 + dd] = outv[j];
    }
}

// ---------------- LayerNorm(x + a) ----------------

__global__ __launch_bounds__(256) void k_ln(float* __restrict__ x, const float* __restrict__ a,
                                            const float* __restrict__ s, const float* __restrict__ b) {
    int row = blockIdx.x;
    int d = threadIdx.x;
    size_t idx = (size_t)row * DM + d;
    float v = x[idx] + a[idx];
    __shared__ float red[8];
    float t = v;
    #pragma unroll
    for (int o = 1; o < 64; o <<= 1) t += __shfl_xor(t, o);
    if ((d & 63) == 0) red[d >> 6] = t;
    __syncthreads();
    float mean = (red[0] + red[1] + red[2] + red[3]) * (1.f / 256.f);
    float c = v - mean;
    float t2 = c * c;
    #pragma unroll
    for (int o = 1; o < 64; o <<= 1) t2 += __shfl_xor(t2, o);
    if ((d & 63) == 0) red[4 + (d >> 6)] = t2;
    __syncthreads();
    float var = (red[4] + red[5] + red[6] + red[7]) * (1.f / 256.f);
    x[idx] = c * rsqrtf(var + 1e-5f) * s[d] + b[d];
}

// ---------------- scores + softmax-over-h + aggregate ----------------

__global__ __launch_bounds__(256) void k_agg(const float* __restrict__ wca,
                                             const float* __restrict__ mc,
                                             float* __restrict__ aggmc) {
    int bs = blockIdx.x; int b = bs >> 6, s = bs & 63;
    int d = threadIdx.x;
    __shared__ float sc[16];
    __shared__ float red[4];
    float mcv = mc[((size_t)b * S_N + s) * DM + d];
    float wv[16];
    #pragma unroll
    for (int h = 0; h < 16; ++h) {
        float w = wca[(((size_t)(b * HT + h)) * S_N + s) * DM + d];
        wv[h] = w;
        float t = w * mcv;
        #pragma unroll
        for (int o = 1; o < 64; o <<= 1) t += __shfl_xor(t, o);
        if ((d & 63) == 0) red[d >> 6] = t;
        __syncthreads();
        if (d == 0) sc[h] = (red[0] + red[1] + red[2] + red[3]) * (1.f / 16.f);
        __syncthreads();
    }
    float mx = -INFINITY;
    #pragma unroll
    for (int h = 0; h < 16; ++h) mx = fmaxf(mx, sc[h]);
    float e[16]; float sum = 0.f;
    #pragma unroll
    for (int h = 0; h < 16; ++h) { e[h] = expf(sc[h] - mx); sum += e[h]; }
    float inv = 1.f / sum;
    float acc = 0.f;
    #pragma unroll
    for (int h = 0; h < 16; ++h) acc += e[h] * inv * wv[h];
    aggmc[((size_t)b * S_N + s) * DM + d] = acc + mcv;
}

// ---------------- launch ----------------

#define GEMM(EPI, BT, A, Bm, bias, resid, Cm, M, N, K) \
    k_gemm<EPI, BT><<<dim3(((N)+63)/64, ((M)+63)/64), 256, 0, stream>>>(A, Bm, bias, resid, Cm, M, N, K)

extern "C" void kernel_launch(void* const* d_in, const int* in_sizes, int n_in,
                              void* d_out, int out_size, void* d_ws, size_t ws_size,
                              hipStream_t stream) {
    const int*   history = (const int*)d_in[0];
    const int*   cur     = (const int*)d_in[1];
    const float* emb     = (const float*)d_in[2];
    const float* nullE   = (const float*)d_in[3];
    const float* gcn_w   = (const float*)d_in[4];
    const float* gcn_b   = (const float*)d_in[5];
    const float* aw      = (const float*)d_in[6];
    const float* ab      = (const float*)d_in[7];
    const float* fw1     = (const float*)d_in[8];
    const float* fb1     = (const float*)d_in[9];
    const float* fw2     = (const float*)d_in[10];
    const float* fb2     = (const float*)d_in[11];
    const float* lns     = (const float*)d_in[12];
    const float* lnb     = (const float*)d_in[13];
    const float* wca_w   = (const float*)d_in[14];
    const float* wca_b   = (const float*)d_in[15];
    const float* ial_w   = (const float*)d_in[16];
    const float* ial_b   = (const float*)d_in[17];
    float* out = (float*)d_out;
    float* ws  = (float*)d_ws;

    // workspace arena (floats)
    float* dvec   = ws + 0;         // 16000
    float* maskb  = ws + 16000;     // 8704
    float* temp   = ws + 24704;     // 16384
    float* aggmc  = ws + 41088;     // 131072
    float* finalb = ws + 172160;    // 65536
    float* SA = ws + 262144;        // 2,228,224 each
    float* SB = ws + 2490368;
    float* SC = ws + 4718592;
    float* SD = ws + 6946816;
    float* SE = ws + 9175040;
    float* SF = ws + 11403264;      // 8,912,896 (ends 20,316,160 floats = 77.5 MiB)

    // --- graph + GCN (sparse: 8064 edges instead of dense 8x2000x2000 A) ---
    hipMemsetAsync(dvec, 0, 16000 * sizeof(float), stream);
    k_colsum<<<(NEDGE + 255) / 256, 256, 0, stream>>>(history, dvec);
    k_dsqrt<<<(B_N * C_N + 255) / 256, 256, 0, stream>>>(dvec);
    k_initX<<<B_N * C_N * DIMN / 256, 256, 0, stream>>>(dvec, emb, SA);
    k_edgeX<<<NEDGE, 128, 0, stream>>>(history, dvec, emb, SA);
    GEMM(3, false, SA, gcn_w, gcn_b, nullptr, SB, B_N * C_N, DIMN, DIMN);  // Eg = relu(X@W+b)

    // --- fuse (batched: 128 history seqs + 8 current seqs) ---
    k_temp<<<S_N, DM, 0, stream>>>(temp);
    k_fuse<<<NSEQ * S_N, DM, 0, stream>>>(history, cur, emb, SB, nullE, temp, SC, maskb);
    float* Xenc = SC;

    // --- encoder, L=2 layers on all 136 sequences ---
    for (int l = 0; l < 2; ++l) {
        const float* Wl = aw + (size_t)l * 4 * DM * DM;
        const float* Bl = ab + (size_t)l * 4 * DM;
        GEMM(1, false, Xenc, Wl + 0 * DM * DM, Bl + 0 * DM, nullptr, SA, NSEQ * S_N, DM, DM);  // Q
        GEMM(1, false, Xenc, Wl + 1 * DM * DM, Bl + 1 * DM, nullptr, SD, NSEQ * S_N, DM, DM);  // K
        GEMM(1, false, Xenc, Wl + 2 * DM * DM, Bl + 2 * DM, nullptr, SE, NSEQ * S_N, DM, DM);  // V
        k_attn<<<NSEQ * 4, 256, 0, stream>>>(SA, SD, SE, maskb, SB);
        GEMM(1, false, SB, Wl + 3 * DM * DM, Bl + 3 * DM, nullptr, SD, NSEQ * S_N, DM, DM);    // O2
        k_ln<<<NSEQ * S_N, DM, 0, stream>>>(Xenc, SD, lns + (l * 2 + 0) * DM, lnb + (l * 2 + 0) * DM);
        GEMM(3, false, Xenc, fw1 + (size_t)l * DM * DFF, fb1 + l * DFF, nullptr, SF, NSEQ * S_N, DFF, DM);
        GEMM(1, false, SF, fw2 + (size_t)l * DFF * DM, fb2 + l * DM, nullptr, SA, NSEQ * S_N, DM, DFF);
        k_ln<<<NSEQ * S_N, DM, 0, stream>>>(Xenc, SA, lns + (l * 2 + 1) * DM, lnb + (l * 2 + 1) * DM);
    }

    float* mh = Xenc;                      // 128 seqs
    float* mc = Xenc + (size_t)128 * S_N * DM;  // 8 seqs

    // --- windowed cross attention ---
    GEMM(1, false, mh, wca_w + 0 * DM * DM, wca_b + 0 * DM, nullptr, SA, 128 * S_N, DM, DM);   // Qw
    GEMM(1, false, mc, wca_w + 1 * DM * DM, wca_b + 1 * DM, nullptr, SD, B_N * S_N, DM, DM);   // Kc
    GEMM(1, false, mc, wca_w + 2 * DM * DM, wca_b + 2 * DM, nullptr, SD + 131072, B_N * S_N, DM, DM); // Vc
    k_attn_wca<<<128 * 4, 256, 0, stream>>>(SA, SD, SD + 131072, SB);
    GEMM(5, false, SB, wca_w + 3 * DM * DM, wca_b + 3 * DM, mh, SE, 128 * S_N, DM, DM);        // wca = mh + proj

    // --- aggregate over trajectories + final projections ---
    k_agg<<<B_N * S_N, DM, 0, stream>>>(SE, mc, aggmc);
    GEMM(3, false, aggmc, ial_w, ial_b, nullptr, finalb, B_N * S_N, DIMN, DM);                 // final = relu(...)
    GEMM(0, true, finalb, emb, nullptr, nullptr, out, B_N * S_N, C_N, DIMN);                   // out = final @ emb^T
}

// Round 2
// 488.684 us; speedup vs baseline: 2.5856x; 2.5856x over previous
//
#include <hip/hip_runtime.h>
#include <hip/hip_bf16.h>
#include <math.h>

#define C_N   2000
#define DIMN  128
#define DM    256
#define B_N   8
#define HT    16
#define S_N   64
#define NSEQ  136
#define DFF   1024
#define NEDGE (B_N*HT*(S_N-1))   // 8064

typedef __hip_bfloat16 bf16;
typedef short bf16x8 __attribute__((ext_vector_type(8)));
typedef float f32x4  __attribute__((ext_vector_type(4)));

#define GLOAD_LDS16(gp, lp) \
    __builtin_amdgcn_global_load_lds((const __attribute__((address_space(1))) void*)(gp), \
                                     (__attribute__((address_space(3))) void*)(lp), 16, 0, 0)

// ---------------- graph / GCN ----------------

__global__ void k_colsum(const int* __restrict__ hist, float* __restrict__ colsum) {
    int e = blockIdx.x * blockDim.x + threadIdx.x;
    if (e >= NEDGE) return;
    int s = e % (S_N-1); int bh = e / (S_N-1); int h = bh % HT; int b = bh / HT;
    const int* row = hist + (size_t)bh * S_N;
    int src = row[s], dst = row[s+1];
    if (src != C_N && dst != C_N && src != dst) {
        float w = 1.f + expf(-0.01f * (float)(HT - 1 - h));
        atomicAdd(&colsum[b * C_N + dst], w);
    }
}

__global__ void k_dsqrt(float* __restrict__ dv) {
    int i = blockIdx.x * blockDim.x + threadIdx.x;
    if (i < B_N * C_N) dv[i] = sqrtf(1.f + dv[i]);
}

__global__ void k_initX(const float* __restrict__ dv, const float* __restrict__ E,
                        float* __restrict__ X) {
    size_t i = (size_t)blockIdx.x * 256 + threadIdx.x;   // over B*C*DIM
    int k = (int)(i % DIMN); size_t bc = i / DIMN;
    int c = (int)(bc % C_N); int b = (int)(bc / C_N);
    float dd = dv[b * C_N + c];
    X[i] = dd * dd * E[(size_t)c * DIMN + k];
}

__global__ void k_edgeX(const int* __restrict__ hist, const float* __restrict__ dv,
                        const float* __restrict__ E, float* __restrict__ X) {
    int e = blockIdx.x;
    int s = e % (S_N-1); int bh = e / (S_N-1); int h = bh % HT; int b = bh / HT;
    const int* row = hist + (size_t)bh * S_N;
    int src = row[s], dst = row[s+1];
    if (src == C_N || dst == C_N || src == dst) return;
    float w = (1.f + expf(-0.01f * (float)(HT - 1 - h))) * dv[b*C_N+src] * dv[b*C_N+dst];
    int k = threadIdx.x;  // 128
    atomicAdd(&X[((size_t)b * C_N + src) * DIMN + k], w * E[(size_t)dst * DIMN + k]);
}

// ---------------- fp32 -> bf16 helpers ----------------

__global__ void k_tobf(const float* __restrict__ s, bf16* __restrict__ d, int n) {
    int i = (blockIdx.x * 256 + threadIdx.x) * 4;
    if (i >= n) return;
    float4 v = *(const float4*)(s + i);
    d[i]   = (bf16)v.x; d[i+1] = (bf16)v.y; d[i+2] = (bf16)v.z; d[i+3] = (bf16)v.w;
}

// src: (nmats, K, N) f32  ->  dst: (nmats*N, K) bf16  (per-matrix transpose)
__global__ void k_transp(const float* __restrict__ src, bf16* __restrict__ dst, int K, int N) {
    __shared__ float t[32][33];
    int mat = blockIdx.z;
    const float* s = src + (size_t)mat * K * N;
    bf16* d = dst + (size_t)mat * N * K;
    int k0 = blockIdx.y * 32, n0 = blockIdx.x * 32;
    #pragma unroll
    for (int j = 0; j < 32; j += 8)
        t[threadIdx.y + j][threadIdx.x] = s[(size_t)(k0 + threadIdx.y + j) * N + n0 + threadIdx.x];
    __syncthreads();
    #pragma unroll
    for (int j = 0; j < 32; j += 8)
        d[(size_t)(n0 + threadIdx.y + j) * K + k0 + threadIdx.x] = (bf16)t[threadIdx.x][threadIdx.y + j];
}

// ---------------- bf16 MFMA GEMM ----------------
// C[M,N] = epi(A[M,K] @ Bt[N,K]^T + bias), EPI: 2=relu, 4=resid(f32, stride N), 8=bf16 out
// Requires: M%128==0, N%64==0, K%64==0. 256 threads, tile 128x64, BK=64.
template<int EPI>
__global__ __launch_bounds__(256) void k_bgemm(
        const bf16* __restrict__ A, const bf16* __restrict__ Bt,
        const float* __restrict__ bias, const float* __restrict__ resid,
        void* __restrict__ Cout, int M, int N, int K)
{
    __shared__ bf16 As[128 * 64];
    __shared__ bf16 Bs[64 * 64];
    int tid = threadIdx.x;
    int wid = tid >> 6, lane = tid & 63;
    int m0 = blockIdx.y * 128, n0 = blockIdx.x * 64;
    int wr = wid >> 1, wc = wid & 1;        // wave sub-tile: 64 rows x 32 cols
    int lr = lane >> 3, lc = lane & 7;
    int gc = lc ^ lr;                       // pre-swizzled global chunk (16B units)
    f32x4 acc[4][2] = {};

    int nkt = K >> 6;
    for (int kt = 0; kt < nkt; ++kt) {
        int kb = kt << 6;
        #pragma unroll
        for (int s = 0; s < 4; ++s) {       // A: 16 segs of 8 rows; 4 per wave
            int seg = wid * 4 + s;
            int row = seg * 8 + lr;
            GLOAD_LDS16(A + (size_t)(m0 + row) * K + kb + gc * 8, As + seg * 512);
        }
        #pragma unroll
        for (int s = 0; s < 2; ++s) {       // B: 8 segs; 2 per wave
            int seg = wid * 2 + s;
            int row = seg * 8 + lr;
            GLOAD_LDS16(Bt + (size_t)(n0 + row) * K + kb + gc * 8, Bs + seg * 512);
        }
        __syncthreads();
        #pragma unroll
        for (int kk = 0; kk < 2; ++kk) {
            bf16x8 af[4], bfr[2];
            int c = kk * 4 + (lane >> 4);
            #pragma unroll
            for (int m = 0; m < 4; ++m) {
                int row = wr * 64 + m * 16 + (lane & 15);
                af[m] = *(const bf16x8*)(As + row * 64 + (c ^ (row & 7)) * 8);
            }
            #pragma unroll
            for (int n = 0; n < 2; ++n) {
                int row = wc * 32 + n * 16 + (lane & 15);
                bfr[n] = *(const bf16x8*)(Bs + row * 64 + (c ^ (row & 7)) * 8);
            }
            #pragma unroll
            for (int m = 0; m < 4; ++m)
                #pragma unroll
                for (int n = 0; n < 2; ++n)
                    acc[m][n] = __builtin_amdgcn_mfma_f32_16x16x32_bf16(af[m], bfr[n], acc[m][n], 0, 0, 0);
        }
        __syncthreads();
    }
    int cl = lane & 15, ch = lane >> 4;
    #pragma unroll
    for (int n = 0; n < 2; ++n) {
        int col = n0 + wc * 32 + n * 16 + cl;
        float bv = bias[col];
        #pragma unroll
        for (int m = 0; m < 4; ++m) {
            #pragma unroll
            for (int j = 0; j < 4; ++j) {
                int row = m0 + wr * 64 + m * 16 + ch * 4 + j;
                float v = acc[m][n][j] + bv;
                if (EPI & 4) v += resid[(size_t)row * N + col];
                if (EPI & 2) v = fmaxf(v, 0.f);
                if (EPI & 8) ((bf16*)Cout)[(size_t)row * N + col] = (bf16)v;
                else         ((float*)Cout)[(size_t)row * N + col] = v;
            }
        }
    }
}

// ---------------- fp32 tiled GEMM (final tail only) ----------------
template<int EPI, bool BTRANS>
__global__ __launch_bounds__(256) void k_gemm(
        const float* __restrict__ A, const float* __restrict__ Bm,
        const float* __restrict__ bias, const float* __restrict__ resid,
        float* __restrict__ Cm, int M, int N, int K)
{
    __shared__ float As[16][65];
    __shared__ float Bs[16][65];
    int tid = threadIdx.x;
    int tx = tid & 15, ty = tid >> 4;
    int m0 = blockIdx.y * 64, n0 = blockIdx.x * 64;
    float acc[4][4] = {};
    for (int k0 = 0; k0 < K; k0 += 16) {
        {
            int mm = tid >> 2;
            int kk = (tid & 3) << 2;
            int m = m0 + mm;
            float4 v = {0,0,0,0};
            if (m < M) v = *(const float4*)(A + (size_t)m * K + k0 + kk);
            As[kk+0][mm] = v.x; As[kk+1][mm] = v.y; As[kk+2][mm] = v.z; As[kk+3][mm] = v.w;
        }
        if (!BTRANS) {
            int kk = tid >> 4;
            int nn = (tid & 15) << 2;
            int n = n0 + nn;
            const float* src = Bm + (size_t)(k0+kk) * N + n;
            float4 v = {0,0,0,0};
            if (n + 3 < N) v = *(const float4*)src;
            else {
                if (n   < N) v.x = src[0];
                if (n+1 < N) v.y = src[1];
                if (n+2 < N) v.z = src[2];
                if (n+3 < N) v.w = src[3];
            }
            Bs[kk][nn] = v.x; Bs[kk][nn+1] = v.y; Bs[kk][nn+2] = v.z; Bs[kk][nn+3] = v.w;
        } else {
            int nn = tid >> 2;
            int kk = (tid & 3) << 2;
            int n = n0 + nn;
            float4 v = {0,0,0,0};
            if (n < N) v = *(const float4*)(Bm + (size_t)n * K + k0 + kk);
            Bs[kk+0][nn] = v.x; Bs[kk+1][nn] = v.y; Bs[kk+2][nn] = v.z; Bs[kk+3][nn] = v.w;
        }
        __syncthreads();
        #pragma unroll
        for (int kk = 0; kk < 16; ++kk) {
            float a[4], b[4];
            #pragma unroll
            for (int i = 0; i < 4; ++i) a[i] = As[kk][ty*4+i];
            #pragma unroll
            for (int j = 0; j < 4; ++j) b[j] = Bs[kk][tx*4+j];
            #pragma unroll
            for (int i = 0; i < 4; ++i)
                #pragma unroll
                for (int j = 0; j < 4; ++j)
                    acc[i][j] = fmaf(a[i], b[j], acc[i][j]);
        }
        __syncthreads();
    }
    #pragma unroll
    for (int i = 0; i < 4; ++i) {
        int m = m0 + ty*4 + i;
        if (m >= M) continue;
        #pragma unroll
        for (int j = 0; j < 4; ++j) {
            int n = n0 + tx*4 + j;
            if (n >= N) continue;
            float v = acc[i][j];
            if (EPI & 1) v += bias[n];
            if (EPI & 4) v += resid[(size_t)m * N + n];
            if (EPI & 2) v = fmaxf(v, 0.f);
            Cm[(size_t)m * N + n] = v;
        }
    }
}

// ---------------- temporal encoding + fuse ----------------

__global__ void k_temp(float* __restrict__ temp) {
    int s = blockIdx.x; int d = threadIdx.x;
    int k = d >> 1;
    float den = powf(10000.f, (2.f * (float)k) / 256.f);
    float arg = (float)s / den;
    temp[s * DM + d] = (d & 1) ? cosf(arg) : sinf(arg);
}

__global__ void k_fuse(const int* __restrict__ hist, const int* __restrict__ cur,
                       const float* __restrict__ E, const float* __restrict__ Eg,
                       const float* __restrict__ nullE, const float* __restrict__ temp,
                       float* __restrict__ Xenc, bf16* __restrict__ Xbf,
                       float* __restrict__ maskb) {
    int blk = blockIdx.x;           // seq*64 + s
    int seq = blk >> 6, s = blk & 63;
    int d = threadIdx.x;
    int idx, b;
    if (seq < 128) { b = seq >> 4; idx = hist[(size_t)seq * S_N + s]; }
    else           { b = seq - 128; idx = cur[b * S_N + s]; }
    float t = temp[s * DM + d];
    float v;
    if (idx == C_N) v = nullE[d] + t;
    else {
        v = ((d < DIMN) ? E[(size_t)idx * DIMN + d]
                        : Eg[((size_t)b * C_N + idx) * DIMN + (d - DIMN)]) + t;
    }
    size_t o = ((size_t)seq * S_N + s) * DM + d;
    Xenc[o] = v;
    Xbf[o]  = (bf16)v;
    if (d == 0) maskb[seq * S_N + s] = (idx == C_N) ? -INFINITY : 0.f;
}

// ---------------- attention (encoder: key-padding mask), QKV fused stride 768 ----------------

__global__ __launch_bounds__(256) void k_attn(
        const float* __restrict__ QKV, const float* __restrict__ maskb,
        bf16* __restrict__ O) {
    int seq = blockIdx.x >> 2, head = blockIdx.x & 3;
    __shared__ float Qs[64][65], Ks[64][65], Vs[64][65];
    __shared__ float mk[64];
    int tid = threadIdx.x;
    int d = tid & 63;
    #pragma unroll
    for (int i = 0; i < 16; ++i) {
        int s = (tid >> 6) + i * 4;
        size_t base = ((size_t)seq * S_N + s) * 768 + head * 64 + d;
        Qs[s][d] = QKV[base]; Ks[s][d] = QKV[base + 256]; Vs[s][d] = QKV[base + 512];
    }
    if (tid < 64) mk[tid] = maskb[seq * S_N + tid];
    __syncthreads();
    int r = tid >> 2, q4 = tid & 3;
    float sc[16];
    #pragma unroll
    for (int j = 0; j < 16; ++j) {
        int c = q4 + j * 4;
        float s = 0.f;
        #pragma unroll 8
        for (int dd = 0; dd < 64; ++dd) s = fmaf(Qs[r][dd], Ks[c][dd], s);
        sc[j] = s * 0.125f + mk[c];
    }
    float mx = sc[0];
    #pragma unroll
    for (int j = 1; j < 16; ++j) mx = fmaxf(mx, sc[j]);
    mx = fmaxf(mx, __shfl_xor(mx, 1));
    mx = fmaxf(mx, __shfl_xor(mx, 2));
    float sum = 0.f;
    #pragma unroll
    for (int j = 0; j < 16; ++j) { sc[j] = expf(sc[j] - mx); sum += sc[j]; }
    sum += __shfl_xor(sum, 1);
    sum += __shfl_xor(sum, 2);
    float inv = 1.f / sum;
    __syncthreads();
    #pragma unroll
    for (int j = 0; j < 16; ++j) Qs[r][q4 + j * 4] = sc[j] * inv;
    __syncthreads();
    #pragma unroll
    for (int j = 0; j < 16; ++j) {
        int dd = q4 + j * 4;
        float s = 0.f;
        #pragma unroll 8
        for (int c = 0; c < 64; ++c) s = fmaf(Qs[r][c], Vs[c][dd], s);
        O[((size_t)seq * S_N + r) * DM + head * 64 + dd] = (bf16)s;
    }
}

// ---------------- attention (WCA: window mask), KV fused stride 512 ----------------

__global__ __launch_bounds__(256) void k_attn_wca(
        const float* __restrict__ Q, const float* __restrict__ KV,
        bf16* __restrict__ O) {
    int seq = blockIdx.x >> 2, head = blockIdx.x & 3;
    int b = seq >> 4;
    __shared__ float Qs[64][65], Ks[64][65], Vs[64][65];
    int tid = threadIdx.x;
    int d = tid & 63;
    #pragma unroll
    for (int i = 0; i < 16; ++i) {
        int s = (tid >> 6) + i * 4;
        Qs[s][d] = Q[((size_t)seq * S_N + s) * DM + head * 64 + d];
        size_t kb = ((size_t)b * S_N + s) * 512 + head * 64 + d;
        Ks[s][d] = KV[kb]; Vs[s][d] = KV[kb + 256];
    }
    __syncthreads();
    int r = tid >> 2, q4 = tid & 3;
    float sc[16];
    #pragma unroll
    for (int j = 0; j < 16; ++j) {
        int c = q4 + j * 4;
        if (abs(r - c) <= 4) {
            float s = 0.f;
            #pragma unroll 8
            for (int dd = 0; dd < 64; ++dd) s = fmaf(Qs[r][dd], Ks[c][dd], s);
            sc[j] = s * 0.125f;
        } else sc[j] = -INFINITY;
    }
    float mx = sc[0];
    #pragma unroll
    for (int j = 1; j < 16; ++j) mx = fmaxf(mx, sc[j]);
    mx = fmaxf(mx, __shfl_xor(mx, 1));
    mx = fmaxf(mx, __shfl_xor(mx, 2));
    float sum = 0.f;
    #pragma unroll
    for (int j = 0; j < 16; ++j) { sc[j] = expf(sc[j] - mx); sum += sc[j]; }
    sum += __shfl_xor(sum, 1);
    sum += __shfl_xor(sum, 2);
    float inv = 1.f / sum;
    __syncthreads();
    #pragma unroll
    for (int j = 0; j < 16; ++j) Qs[r][q4 + j * 4] = sc[j] * inv;
    __syncthreads();
    #pragma unroll
    for (int j = 0; j < 16; ++j) {
        int dd = q4 + j * 4;
        float s = 0.f;
        #pragma unroll 8
        for (int c = 0; c < 64; ++c) s = fmaf(Qs[r][c], Vs[c][dd], s);
        O[((size_t)seq * S_N + r) * DM + head * 64 + dd] = (bf16)s;
    }
}

// ---------------- LayerNorm(x + a), writes f32 + bf16 ----------------

__global__ __launch_bounds__(256) void k_ln(float* __restrict__ x, const float* __restrict__ a,
                                            const float* __restrict__ s, const float* __restrict__ b,
                                            bf16* __restrict__ xbf) {
    int row = blockIdx.x;
    int d = threadIdx.x;
    size_t idx = (size_t)row * DM + d;
    float v = x[idx] + a[idx];
    __shared__ float red[8];
    float t = v;
    #pragma unroll
    for (int o = 1; o < 64; o <<= 1) t += __shfl_xor(t, o);
    if ((d & 63) == 0) red[d >> 6] = t;
    __syncthreads();
    float mean = (red[0] + red[1] + red[2] + red[3]) * (1.f / 256.f);
    float c = v - mean;
    float t2 = c * c;
    #pragma unroll
    for (int o = 1; o < 64; o <<= 1) t2 += __shfl_xor(t2, o);
    if ((d & 63) == 0) red[4 + (d >> 6)] = t2;
    __syncthreads();
    float var = (red[4] + red[5] + red[6] + red[7]) * (1.f / 256.f);
    float r = c * rsqrtf(var + 1e-5f) * s[d] + b[d];
    x[idx] = r;
    xbf[idx] = (bf16)r;
}

// ---------------- scores + softmax-over-h + aggregate ----------------

__global__ __launch_bounds__(256) void k_agg(const float* __restrict__ wca,
                                             const float* __restrict__ mc,
                                             float* __restrict__ aggmc) {
    int bs = blockIdx.x; int b = bs >> 6, s = bs & 63;
    int d = threadIdx.x;
    __shared__ float sc[16];
    __shared__ float red[4];
    float mcv = mc[((size_t)b * S_N + s) * DM + d];
    float wv[16];
    #pragma unroll
    for (int h = 0; h < 16; ++h) {
        float w = wca[(((size_t)(b * HT + h)) * S_N + s) * DM + d];
        wv[h] = w;
        float t = w * mcv;
        #pragma unroll
        for (int o = 1; o < 64; o <<= 1) t += __shfl_xor(t, o);
        if ((d & 63) == 0) red[d >> 6] = t;
        __syncthreads();
        if (d == 0) sc[h] = (red[0] + red[1] + red[2] + red[3]) * (1.f / 16.f);
        __syncthreads();
    }
    float mx = -INFINITY;
    #pragma unroll
    for (int h = 0; h < 16; ++h) mx = fmaxf(mx, sc[h]);
    float e[16]; float sum = 0.f;
    #pragma unroll
    for (int h = 0; h < 16; ++h) { e[h] = expf(sc[h] - mx); sum += e[h]; }
    float inv = 1.f / sum;
    float acc = 0.f;
    #pragma unroll
    for (int h = 0; h < 16; ++h) acc += e[h] * inv * wv[h];
    aggmc[((size_t)b * S_N + s) * DM + d] = acc + mcv;
}

// ---------------- launch ----------------

extern "C" void kernel_launch(void* const* d_in, const int* in_sizes, int n_in,
                              void* d_out, int out_size, void* d_ws, size_t ws_size,
                              hipStream_t stream) {
    const int*   history = (const int*)d_in[0];
    const int*   cur     = (const int*)d_in[1];
    const float* emb     = (const float*)d_in[2];
    const float* nullE   = (const float*)d_in[3];
    const float* gcn_w   = (const float*)d_in[4];
    const float* gcn_b   = (const float*)d_in[5];
    const float* aw      = (const float*)d_in[6];
    const float* ab      = (const float*)d_in[7];
    const float* fw1     = (const float*)d_in[8];
    const float* fb1     = (const float*)d_in[9];
    const float* fw2     = (const float*)d_in[10];
    const float* fb2     = (const float*)d_in[11];
    const float* lns     = (const float*)d_in[12];
    const float* lnb     = (const float*)d_in[13];
    const float* wca_w   = (const float*)d_in[14];
    const float* wca_b   = (const float*)d_in[15];
    const float* ial_w   = (const float*)d_in[16];
    const float* ial_b   = (const float*)d_in[17];
    float* out = (float*)d_out;
    float* ws  = (float*)d_ws;

    // ---- arena (float offsets; total 18,989,184 f = 72.4 MiB) ----
    float* dvec   = ws + 0;            // 16,000
    float* maskb  = ws + 16000;        // 8,704
    float* temp   = ws + 24704;        // 16,384
    float* aggmc  = ws + 41088;        // 131,072
    float* finalb = ws + 172160;       // 65,536
    bf16*  wbf    = (bf16*)(ws + 237696);       // 1,851,392 bf16 = 925,696 f
    float* Xenc   = ws + 1163392;      // 2,228,224
    bf16*  Xbf    = (bf16*)(ws + 3391616);      // 2,228,224 bf16
    bf16*  Abf    = (bf16*)(ws + 4505728);      // 2,228,224 bf16
    bf16*  Hbf    = (bf16*)(ws + 5619840);      // 8,912,896 bf16
    float* QKVf   = ws + 10076288;     // 6,684,672
    float* O2     = ws + 16760960;     // 2,228,224

    // bf16 weight sub-arena
    bf16* wbf_aw  = wbf;               // 8 mats of 256x256 -> (2048,256)
    bf16* wbf_fw1 = wbf + 524288;      // (2048,256)
    bf16* wbf_fw2 = wbf + 1048576;     // (512,1024)
    bf16* wbf_wca = wbf + 1572864;     // (1024,256)
    bf16* wbf_gcn = wbf + 1835008;     // (128,128)

    // phase aliases
    float* Xg   = QKVf;                // GCN input f32 (16000x128)
    bf16*  Xgbf = Hbf;                 // GCN input bf16
    float* Eg   = O2;                  // GCN output (16000x128)
    float* Qwf  = QKVf;                // WCA Q (8192x256)
    float* KVf  = QKVf + 2097152;      // WCA KV (512x512)
    float* SE   = QKVf + 2359296;      // wca out f32 (8192x256)

    // --- weight convert+transpose (f32 -> bf16 (N,K)) ---
    k_transp<<<dim3(8, 8, 8),  dim3(32, 8), 0, stream>>>(aw,    wbf_aw, 256, 256);
    k_transp<<<dim3(32, 8, 2), dim3(32, 8), 0, stream>>>(fw1,   wbf_fw1, 256, 1024);
    k_transp<<<dim3(8, 32, 2), dim3(32, 8), 0, stream>>>(fw2,   wbf_fw2, 1024, 256);
    k_transp<<<dim3(8, 8, 4),  dim3(32, 8), 0, stream>>>(wca_w, wbf_wca, 256, 256);
    k_transp<<<dim3(4, 4, 1),  dim3(32, 8), 0, stream>>>(gcn_w, wbf_gcn, 128, 128);

    // --- graph + GCN (sparse) ---
    hipMemsetAsync(dvec, 0, 16000 * sizeof(float), stream);
    k_colsum<<<(NEDGE + 255) / 256, 256, 0, stream>>>(history, dvec);
    k_dsqrt<<<(B_N * C_N + 255) / 256, 256, 0, stream>>>(dvec);
    k_initX<<<B_N * C_N * DIMN / 256, 256, 0, stream>>>(dvec, emb, Xg);
    k_edgeX<<<NEDGE, 128, 0, stream>>>(history, dvec, emb, Xg);
    k_tobf<<<2000, 256, 0, stream>>>(Xg, Xgbf, B_N * C_N * DIMN);
    k_bgemm<2><<<dim3(2, 125), 256, 0, stream>>>(Xgbf, wbf_gcn, gcn_b, nullptr, Eg,
                                                 B_N * C_N, DIMN, DIMN);

    // --- fuse ---
    k_temp<<<S_N, DM, 0, stream>>>(temp);
    k_fuse<<<NSEQ * S_N, DM, 0, stream>>>(history, cur, emb, Eg, nullE, temp, Xenc, Xbf, maskb);

    // --- encoder, L=2 ---
    for (int l = 0; l < 2; ++l) {
        k_bgemm<0><<<dim3(12, 68), 256, 0, stream>>>(Xbf, wbf_aw + l * 262144,
                ab + l * 1024, nullptr, QKVf, NSEQ * S_N, 768, 256);
        k_attn<<<NSEQ * 4, 256, 0, stream>>>(QKVf, maskb, Abf);
        k_bgemm<0><<<dim3(4, 68), 256, 0, stream>>>(Abf, wbf_aw + l * 262144 + 196608,
                ab + l * 1024 + 768, nullptr, O2, NSEQ * S_N, 256, 256);
        k_ln<<<NSEQ * S_N, DM, 0, stream>>>(Xenc, O2, lns + (l * 2 + 0) * DM, lnb + (l * 2 + 0) * DM, Xbf);
        k_bgemm<10><<<dim3(16, 68), 256, 0, stream>>>(Xbf, wbf_fw1 + l * 262144,
                fb1 + l * DFF, nullptr, Hbf, NSEQ * S_N, DFF, 256);
        k_bgemm<0><<<dim3(4, 68), 256, 0, stream>>>(Hbf, wbf_fw2 + l * 262144,
                fb2 + l * DM, nullptr, O2, NSEQ * S_N, 256, 1024);
        k_ln<<<NSEQ * S_N, DM, 0, stream>>>(Xenc, O2, lns + (l * 2 + 1) * DM, lnb + (l * 2 + 1) * DM, Xbf);
    }

    float* mh = Xenc;                            // 128 seqs f32
    bf16*  mc_bf = Xbf + (size_t)128 * S_N * DM; // 8 seqs bf16

    // --- windowed cross attention ---
    k_bgemm<0><<<dim3(4, 64), 256, 0, stream>>>(Xbf, wbf_wca, wca_b, nullptr, Qwf,
                                                128 * S_N, 256, 256);
    k_bgemm<0><<<dim3(8, 4), 256, 0, stream>>>(mc_bf, wbf_wca + 65536, wca_b + 256, nullptr, KVf,
                                               B_N * S_N, 512, 256);
    k_attn_wca<<<128 * 4, 256, 0, stream>>>(Qwf, KVf, Abf);
    k_bgemm<4><<<dim3(4, 64), 256, 0, stream>>>(Abf, wbf_wca + 196608, wca_b + 768, mh, SE,
                                                128 * S_N, 256, 256);

    // --- aggregate + final (fp32 tail for accuracy) ---
    k_agg<<<B_N * S_N, DM, 0, stream>>>(SE, Xenc + (size_t)128 * S_N * DM, aggmc);
    k_gemm<3, false><<<dim3(2, 8), 256, 0, stream>>>(aggmc, ial_w, ial_b, nullptr, finalb,
                                                     B_N * S_N, DIMN, DM);
    k_gemm<0, true><<<dim3(32, 8), 256, 0, stream>>>(finalb, emb, nullptr, nullptr, out,
                                                     B_N * S_N, C_N, DIMN);
}

// Round 4
// 380.566 us; speedup vs baseline: 3.3201x; 1.2841x over previous
//
#include <hip/hip_runtime.h>
#include <hip/hip_bf16.h>
#include <math.h>

#define C_N   2000
#define DIMN  128
#define DM    256
#define B_N   8
#define HT    16
#define S_N   64
#define NSEQ  136
#define DFF   1024
#define NEDGE (B_N*HT*(S_N-1))   // 8064

typedef __hip_bfloat16 bf16;
typedef short bf16x8 __attribute__((ext_vector_type(8)));
typedef float f32x4  __attribute__((ext_vector_type(4)));

#define GLOAD_LDS16(gp, lp) \
    __builtin_amdgcn_global_load_lds((const __attribute__((address_space(1))) void*)(gp), \
                                     (__attribute__((address_space(3))) void*)(lp), 16, 0, 0)

__device__ __forceinline__ short f2bf(float v) {
    bf16 t = (bf16)v;
    return *reinterpret_cast<short*>(&t);
}

// ---------------- graph / GCN ----------------

__global__ void k_colsum(const int* __restrict__ hist, float* __restrict__ colsum) {
    int e = blockIdx.x * blockDim.x + threadIdx.x;
    if (e >= NEDGE) return;
    int s = e % (S_N-1); int bh = e / (S_N-1); int h = bh % HT; int b = bh / HT;
    const int* row = hist + (size_t)bh * S_N;
    int src = row[s], dst = row[s+1];
    if (src != C_N && dst != C_N && src != dst) {
        float w = 1.f + expf(-0.01f * (float)(HT - 1 - h));
        atomicAdd(&colsum[b * C_N + dst], w);
    }
}

__global__ void k_dsqrt(float* __restrict__ dv) {
    int i = blockIdx.x * blockDim.x + threadIdx.x;
    if (i < B_N * C_N) dv[i] = sqrtf(1.f + dv[i]);
}

__global__ void k_initX(const float* __restrict__ dv, const float* __restrict__ E,
                        float* __restrict__ X) {
    size_t i = (size_t)blockIdx.x * 256 + threadIdx.x;   // over B*C*DIM
    int k = (int)(i % DIMN); size_t bc = i / DIMN;
    int c = (int)(bc % C_N); int b = (int)(bc / C_N);
    float dd = dv[b * C_N + c];
    X[i] = dd * dd * E[(size_t)c * DIMN + k];
}

__global__ void k_edgeX(const int* __restrict__ hist, const float* __restrict__ dv,
                        const float* __restrict__ E, float* __restrict__ X) {
    int e = blockIdx.x;
    int s = e % (S_N-1); int bh = e / (S_N-1); int h = bh % HT; int b = bh / HT;
    const int* row = hist + (size_t)bh * S_N;
    int src = row[s], dst = row[s+1];
    if (src == C_N || dst == C_N || src == dst) return;
    float w = (1.f + expf(-0.01f * (float)(HT - 1 - h))) * dv[b*C_N+src] * dv[b*C_N+dst];
    int k = threadIdx.x;  // 128
    atomicAdd(&X[((size_t)b * C_N + src) * DIMN + k], w * E[(size_t)dst * DIMN + k]);
}

// ---------------- fp32 -> bf16 helpers ----------------

__global__ void k_tobf(const float* __restrict__ s, bf16* __restrict__ d, int n) {
    int i = (blockIdx.x * 256 + threadIdx.x) * 4;
    if (i >= n) return;
    float4 v = *(const float4*)(s + i);
    d[i]   = (bf16)v.x; d[i+1] = (bf16)v.y; d[i+2] = (bf16)v.z; d[i+3] = (bf16)v.w;
}

// src: (nmats, K, N) f32  ->  dst: (nmats*N, K) bf16  (per-matrix transpose)
__global__ void k_transp(const float* __restrict__ src, bf16* __restrict__ dst, int K, int N) {
    __shared__ float t[32][33];
    int mat = blockIdx.z;
    const float* s = src + (size_t)mat * K * N;
    bf16* d = dst + (size_t)mat * N * K;
    int k0 = blockIdx.y * 32, n0 = blockIdx.x * 32;
    #pragma unroll
    for (int j = 0; j < 32; j += 8)
        t[threadIdx.y + j][threadIdx.x] = s[(size_t)(k0 + threadIdx.y + j) * N + n0 + threadIdx.x];
    __syncthreads();
    #pragma unroll
    for (int j = 0; j < 32; j += 8)
        d[(size_t)(n0 + threadIdx.y + j) * K + k0 + threadIdx.x] = (bf16)t[threadIdx.x][threadIdx.y + j];
}

// ---------------- bf16 MFMA GEMM ----------------
// C[M,N] = epi(A[M,K] @ Bt[N,K]^T + bias), EPI: 2=relu, 4=resid(f32, stride N), 8=bf16 out
// Requires: M%128==0, N%64==0, K%64==0. 256 threads, tile 128x64, BK=64.
template<int EPI>
__global__ __launch_bounds__(256) void k_bgemm(
        const bf16* __restrict__ A, const bf16* __restrict__ Bt,
        const float* __restrict__ bias, const float* __restrict__ resid,
        void* __restrict__ Cout, int M, int N, int K)
{
    __shared__ bf16 As[128 * 64];
    __shared__ bf16 Bs[64 * 64];
    int tid = threadIdx.x;
    int wid = tid >> 6, lane = tid & 63;
    int m0 = blockIdx.y * 128, n0 = blockIdx.x * 64;
    int wr = wid >> 1, wc = wid & 1;        // wave sub-tile: 64 rows x 32 cols
    int lr = lane >> 3, lc = lane & 7;
    int gc = lc ^ lr;                       // pre-swizzled global chunk (16B units)
    f32x4 acc[4][2] = {};

    int nkt = K >> 6;
    for (int kt = 0; kt < nkt; ++kt) {
        int kb = kt << 6;
        #pragma unroll
        for (int s = 0; s < 4; ++s) {       // A: 16 segs of 8 rows; 4 per wave
            int seg = wid * 4 + s;
            int row = seg * 8 + lr;
            GLOAD_LDS16(A + (size_t)(m0 + row) * K + kb + gc * 8, As + seg * 512);
        }
        #pragma unroll
        for (int s = 0; s < 2; ++s) {       // B: 8 segs; 2 per wave
            int seg = wid * 2 + s;
            int row = seg * 8 + lr;
            GLOAD_LDS16(Bt + (size_t)(n0 + row) * K + kb + gc * 8, Bs + seg * 512);
        }
        __syncthreads();
        #pragma unroll
        for (int kk = 0; kk < 2; ++kk) {
            bf16x8 af[4], bfr[2];
            int c = kk * 4 + (lane >> 4);
            #pragma unroll
            for (int m = 0; m < 4; ++m) {
                int row = wr * 64 + m * 16 + (lane & 15);
                af[m] = *(const bf16x8*)(As + row * 64 + (c ^ (row & 7)) * 8);
            }
            #pragma unroll
            for (int n = 0; n < 2; ++n) {
                int row = wc * 32 + n * 16 + (lane & 15);
                bfr[n] = *(const bf16x8*)(Bs + row * 64 + (c ^ (row & 7)) * 8);
            }
            #pragma unroll
            for (int m = 0; m < 4; ++m)
                #pragma unroll
                for (int n = 0; n < 2; ++n)
                    acc[m][n] = __builtin_amdgcn_mfma_f32_16x16x32_bf16(af[m], bfr[n], acc[m][n], 0, 0, 0);
        }
        __syncthreads();
    }
    int cl = lane & 15, ch = lane >> 4;
    #pragma unroll
    for (int n = 0; n < 2; ++n) {
        int col = n0 + wc * 32 + n * 16 + cl;
        float bv = bias[col];
        #pragma unroll
        for (int m = 0; m < 4; ++m) {
            #pragma unroll
            for (int j = 0; j < 4; ++j) {
                int row = m0 + wr * 64 + m * 16 + ch * 4 + j;
                float v = acc[m][n][j] + bv;
                if (EPI & 4) v += resid[(size_t)row * N + col];
                if (EPI & 2) v = fmaxf(v, 0.f);
                if (EPI & 8) ((bf16*)Cout)[(size_t)row * N + col] = (bf16)v;
                else         ((float*)Cout)[(size_t)row * N + col] = v;
            }
        }
    }
}

// ---------------- fp32 tiled GEMM (final tail only) ----------------
template<int EPI, bool BTRANS>
__global__ __launch_bounds__(256) void k_gemm(
        const float* __restrict__ A, const float* __restrict__ Bm,
        const float* __restrict__ bias, const float* __restrict__ resid,
        float* __restrict__ Cm, int M, int N, int K)
{
    __shared__ float As[16][65];
    __shared__ float Bs[16][65];
    int tid = threadIdx.x;
    int tx = tid & 15, ty = tid >> 4;
    int m0 = blockIdx.y * 64, n0 = blockIdx.x * 64;
    float acc[4][4] = {};
    for (int k0 = 0; k0 < K; k0 += 16) {
        {
            int mm = tid >> 2;
            int kk = (tid & 3) << 2;
            int m = m0 + mm;
            float4 v = {0,0,0,0};
            if (m < M) v = *(const float4*)(A + (size_t)m * K + k0 + kk);
            As[kk+0][mm] = v.x; As[kk+1][mm] = v.y; As[kk+2][mm] = v.z; As[kk+3][mm] = v.w;
        }
        if (!BTRANS) {
            int kk = tid >> 4;
            int nn = (tid & 15) << 2;
            int n = n0 + nn;
            const float* src = Bm + (size_t)(k0+kk) * N + n;
            float4 v = {0,0,0,0};
            if (n + 3 < N) v = *(const float4*)src;
            else {
                if (n   < N) v.x = src[0];
                if (n+1 < N) v.y = src[1];
                if (n+2 < N) v.z = src[2];
                if (n+3 < N) v.w = src[3];
            }
            Bs[kk][nn] = v.x; Bs[kk][nn+1] = v.y; Bs[kk][nn+2] = v.z; Bs[kk][nn+3] = v.w;
        } else {
            int nn = tid >> 2;
            int kk = (tid & 3) << 2;
            int n = n0 + nn;
            float4 v = {0,0,0,0};
            if (n < N) v = *(const float4*)(Bm + (size_t)n * K + k0 + kk);
            Bs[kk+0][nn] = v.x; Bs[kk+1][nn] = v.y; Bs[kk+2][nn] = v.z; Bs[kk+3][nn] = v.w;
        }
        __syncthreads();
        #pragma unroll
        for (int kk = 0; kk < 16; ++kk) {
            float a[4], b[4];
            #pragma unroll
            for (int i = 0; i < 4; ++i) a[i] = As[kk][ty*4+i];
            #pragma unroll
            for (int j = 0; j < 4; ++j) b[j] = Bs[kk][tx*4+j];
            #pragma unroll
            for (int i = 0; i < 4; ++i)
                #pragma unroll
                for (int j = 0; j < 4; ++j)
                    acc[i][j] = fmaf(a[i], b[j], acc[i][j]);
        }
        __syncthreads();
    }
    #pragma unroll
    for (int i = 0; i < 4; ++i) {
        int m = m0 + ty*4 + i;
        if (m >= M) continue;
        #pragma unroll
        for (int j = 0; j < 4; ++j) {
            int n = n0 + tx*4 + j;
            if (n >= N) continue;
            float v = acc[i][j];
            if (EPI & 1) v += bias[n];
            if (EPI & 4) v += resid[(size_t)m * N + n];
            if (EPI & 2) v = fmaxf(v, 0.f);
            Cm[(size_t)m * N + n] = v;
        }
    }
}

// ---------------- temporal encoding + fuse ----------------

__global__ void k_temp(float* __restrict__ temp) {
    int s = blockIdx.x; int d = threadIdx.x;
    int k = d >> 1;
    float den = powf(10000.f, (2.f * (float)k) / 256.f);
    float arg = (float)s / den;
    temp[s * DM + d] = (d & 1) ? cosf(arg) : sinf(arg);
}

__global__ void k_fuse(const int* __restrict__ hist, const int* __restrict__ cur,
                       const float* __restrict__ E, const float* __restrict__ Eg,
                       const float* __restrict__ nullE, const float* __restrict__ temp,
                       float* __restrict__ Xenc, bf16* __restrict__ Xbf,
                       float* __restrict__ maskb) {
    int blk = blockIdx.x;           // seq*64 + s
    int seq = blk >> 6, s = blk & 63;
    int d = threadIdx.x;
    int idx, b;
    if (seq < 128) { b = seq >> 4; idx = hist[(size_t)seq * S_N + s]; }
    else           { b = seq - 128; idx = cur[b * S_N + s]; }
    float t = temp[s * DM + d];
    float v;
    if (idx == C_N) v = nullE[d] + t;
    else {
        v = ((d < DIMN) ? E[(size_t)idx * DIMN + d]
                        : Eg[((size_t)b * C_N + idx) * DIMN + (d - DIMN)]) + t;
    }
    size_t o = ((size_t)seq * S_N + s) * DM + d;
    Xenc[o] = v;
    Xbf[o]  = (bf16)v;
    if (d == 0) maskb[seq * S_N + s] = (idx == C_N) ? -INFINITY : 0.f;
}

// ---------------- MFMA attention: one wave per (seq, head) ----------------
// Qb/Kb/Vb: bf16, row strides qstr/kstr. Encoder (WCA=false): key-padding mask
// from maskb. WCA=true: window mask |q-k|<=4, KV indexed by seq>>4.
// O: bf16 [*, 256], head h at cols h*64..h*64+63.
template<bool WCA>
__global__ __launch_bounds__(64) void k_mattn(
        const bf16* __restrict__ Qb, const bf16* __restrict__ Kb,
        const bf16* __restrict__ Vb, const float* __restrict__ maskb,
        bf16* __restrict__ O, int qstr, int kstr)
{
    int seq = blockIdx.x >> 2, head = blockIdx.x & 3;
    int lane = threadIdx.x;
    int cl = lane & 15, ch = lane >> 4;
    __shared__ __align__(16) short VT[64 * 72];   // V^T [d][k]
    __shared__ __align__(16) short PT[64 * 72];   // P [q][k]; later reused for O staging

    const bf16* Qp = Qb + (size_t)seq * 64 * qstr + head * 64;
    int kvseq = WCA ? (seq >> 4) : seq;
    const bf16* Kp = Kb + (size_t)kvseq * 64 * kstr + head * 64;
    const bf16* Vp = Vb + (size_t)kvseq * 64 * kstr + head * 64;

    // fragment loads: A/B operand of 16x16x32 = row (lane&15), 8 k-elems at (lane>>4)*8
    bf16x8 aq[4][2], bk[4][2], vr[4][2];
    #pragma unroll
    for (int t = 0; t < 4; ++t)
        #pragma unroll
        for (int kk = 0; kk < 2; ++kk) {
            int row = t * 16 + cl, d0 = kk * 32 + ch * 8;
            aq[t][kk] = *(const bf16x8*)(Qp + (size_t)row * qstr + d0);
            bk[t][kk] = *(const bf16x8*)(Kp + (size_t)row * kstr + d0);
            vr[t][kk] = *(const bf16x8*)(Vp + (size_t)row * kstr + d0);
        }

    // S = Q @ K^T  (rows q, cols k)
    f32x4 sa[4][4] = {};
    #pragma unroll
    for (int kk = 0; kk < 2; ++kk)
        #pragma unroll
        for (int m = 0; m < 4; ++m)
            #pragma unroll
            for (int n = 0; n < 4; ++n)
                sa[m][n] = __builtin_amdgcn_mfma_f32_16x16x32_bf16(aq[m][kk], bk[n][kk], sa[m][n], 0, 0, 0);

    // stage V^T into LDS (token-contiguous for the PV contraction)
    #pragma unroll
    for (int t = 0; t < 4; ++t)
        #pragma unroll
        for (int kk = 0; kk < 2; ++kk) {
            int k = t * 16 + cl, d0 = kk * 32 + ch * 8;
            #pragma unroll
            for (int e = 0; e < 8; ++e)
                VT[(d0 + e) * 72 + k] = vr[t][kk][e];
        }

    // mask terms
    float mk4[4];
    if (!WCA) {
        #pragma unroll
        for (int n = 0; n < 4; ++n) mk4[n] = maskb[seq * 64 + n * 16 + cl];
    }

    // softmax over k (per q-row): local over n, cross-lane over the 16-lane group
    #pragma unroll
    for (int m = 0; m < 4; ++m) {
        #pragma unroll
        for (int j = 0; j < 4; ++j) {
            int q = m * 16 + ch * 4 + j;
            float rm = -INFINITY;
            #pragma unroll
            for (int n = 0; n < 4; ++n) {
                int k = n * 16 + cl;
                float msk = WCA ? ((abs(q - k) <= 4) ? 0.f : -INFINITY) : mk4[n];
                float v = sa[m][n][j] * 0.125f + msk;
                sa[m][n][j] = v;
                rm = fmaxf(rm, v);
            }
            rm = fmaxf(rm, __shfl_xor(rm, 1));
            rm = fmaxf(rm, __shfl_xor(rm, 2));
            rm = fmaxf(rm, __shfl_xor(rm, 4));
            rm = fmaxf(rm, __shfl_xor(rm, 8));
            float rs = 0.f;
            #pragma unroll
            for (int n = 0; n < 4; ++n) {
                float e = expf(sa[m][n][j] - rm);
                sa[m][n][j] = e;
                rs += e;
            }
            rs += __shfl_xor(rs, 1);
            rs += __shfl_xor(rs, 2);
            rs += __shfl_xor(rs, 4);
            rs += __shfl_xor(rs, 8);
            float inv = 1.f / rs;
            #pragma unroll
            for (int n = 0; n < 4; ++n)
                PT[q * 72 + n * 16 + cl] = f2bf(sa[m][n][j] * inv);
        }
    }
    __syncthreads();

    // O^T = V^T @ P^T   (rows d, cols q; contraction over tokens k)
    f32x4 oa[4][4] = {};
    #pragma unroll
    for (int kk = 0; kk < 2; ++kk) {
        bf16x8 av[4], bp[4];
        #pragma unroll
        for (int dm = 0; dm < 4; ++dm)
            av[dm] = *(const bf16x8*)(VT + (dm * 16 + cl) * 72 + kk * 32 + ch * 8);
        #pragma unroll
        for (int qn = 0; qn < 4; ++qn)
            bp[qn] = *(const bf16x8*)(PT + (qn * 16 + cl) * 72 + kk * 32 + ch * 8);
        #pragma unroll
        for (int dm = 0; dm < 4; ++dm)
            #pragma unroll
            for (int qn = 0; qn < 4; ++qn)
                oa[dm][qn] = __builtin_amdgcn_mfma_f32_16x16x32_bf16(av[dm], bp[qn], oa[dm][qn], 0, 0, 0);
    }
    __syncthreads();

    // stage O^T back as [q][d] for coalesced global write
    #pragma unroll
    for (int dm = 0; dm < 4; ++dm)
        #pragma unroll
        for (int qn = 0; qn < 4; ++qn)
            #pragma unroll
            for (int j = 0; j < 4; ++j)
                PT[(qn * 16 + cl) * 72 + dm * 16 + ch * 4 + j] = f2bf(oa[dm][qn][j]);
    __syncthreads();
    #pragma unroll
    for (int it = 0; it < 8; ++it) {       // 512 chunks of 8 bf16 = 64 tok x 64 d
        int chunk = it * 64 + lane;
        int tok = chunk >> 3, d0 = (chunk & 7) * 8;
        bf16x8 v = *(const bf16x8*)(PT + tok * 72 + d0);
        *(bf16x8*)(O + ((size_t)seq * 64 + tok) * 256 + head * 64 + d0) = v;
    }
}

// ---------------- LayerNorm(x + a), writes f32 + bf16 ----------------

__global__ __launch_bounds__(256) void k_ln(float* __restrict__ x, const float* __restrict__ a,
                                            const float* __restrict__ s, const float* __restrict__ b,
                                            bf16* __restrict__ xbf) {
    int row = blockIdx.x;
    int d = threadIdx.x;
    size_t idx = (size_t)row * DM + d;
    float v = x[idx] + a[idx];
    __shared__ float red[8];
    float t = v;
    #pragma unroll
    for (int o = 1; o < 64; o <<= 1) t += __shfl_xor(t, o);
    if ((d & 63) == 0) red[d >> 6] = t;
    __syncthreads();
    float mean = (red[0] + red[1] + red[2] + red[3]) * (1.f / 256.f);
    float c = v - mean;
    float t2 = c * c;
    #pragma unroll
    for (int o = 1; o < 64; o <<= 1) t2 += __shfl_xor(t2, o);
    if ((d & 63) == 0) red[4 + (d >> 6)] = t2;
    __syncthreads();
    float var = (red[4] + red[5] + red[6] + red[7]) * (1.f / 256.f);
    float r = c * rsqrtf(var + 1e-5f) * s[d] + b[d];
    x[idx] = r;
    xbf[idx] = (bf16)r;
}

// ---------------- scores + softmax-over-h + aggregate ----------------

__global__ __launch_bounds__(256) void k_agg(const float* __restrict__ wca,
                                             const float* __restrict__ mc,
                                             float* __restrict__ aggmc) {
    int bs = blockIdx.x; int b = bs >> 6, s = bs & 63;
    int d = threadIdx.x;
    __shared__ float sc[16];
    __shared__ float red[4];
    float mcv = mc[((size_t)b * S_N + s) * DM + d];
    float wv[16];
    #pragma unroll
    for (int h = 0; h < 16; ++h) {
        float w = wca[(((size_t)(b * HT + h)) * S_N + s) * DM + d];
        wv[h] = w;
        float t = w * mcv;
        #pragma unroll
        for (int o = 1; o < 64; o <<= 1) t += __shfl_xor(t, o);
        if ((d & 63) == 0) red[d >> 6] = t;
        __syncthreads();
        if (d == 0) sc[h] = (red[0] + red[1] + red[2] + red[3]) * (1.f / 16.f);
        __syncthreads();
    }
    float mx = -INFINITY;
    #pragma unroll
    for (int h = 0; h < 16; ++h) mx = fmaxf(mx, sc[h]);
    float e[16]; float sum = 0.f;
    #pragma unroll
    for (int h = 0; h < 16; ++h) { e[h] = expf(sc[h] - mx); sum += e[h]; }
    float inv = 1.f / sum;
    float acc = 0.f;
    #pragma unroll
    for (int h = 0; h < 16; ++h) acc += e[h] * inv * wv[h];
    aggmc[((size_t)b * S_N + s) * DM + d] = acc + mcv;
}

// ---------------- launch ----------------

extern "C" void kernel_launch(void* const* d_in, const int* in_sizes, int n_in,
                              void* d_out, int out_size, void* d_ws, size_t ws_size,
                              hipStream_t stream) {
    const int*   history = (const int*)d_in[0];
    const int*   cur     = (const int*)d_in[1];
    const float* emb     = (const float*)d_in[2];
    const float* nullE   = (const float*)d_in[3];
    const float* gcn_w   = (const float*)d_in[4];
    const float* gcn_b   = (const float*)d_in[5];
    const float* aw      = (const float*)d_in[6];
    const float* ab      = (const float*)d_in[7];
    const float* fw1     = (const float*)d_in[8];
    const float* fb1     = (const float*)d_in[9];
    const float* fw2     = (const float*)d_in[10];
    const float* fb2     = (const float*)d_in[11];
    const float* lns     = (const float*)d_in[12];
    const float* lnb     = (const float*)d_in[13];
    const float* wca_w   = (const float*)d_in[14];
    const float* wca_b   = (const float*)d_in[15];
    const float* ial_w   = (const float*)d_in[16];
    const float* ial_b   = (const float*)d_in[17];
    float* out = (float*)d_out;
    float* ws  = (float*)d_ws;

    // ---- arena (float offsets) ----
    float* dvec   = ws + 0;            // 16,000
    float* maskb  = ws + 16000;        // 8,704
    float* temp   = ws + 24704;        // 16,384
    float* aggmc  = ws + 41088;        // 131,072
    float* finalb = ws + 172160;       // 65,536
    bf16*  wbf    = (bf16*)(ws + 237696);        // 1,851,392 bf16
    float* Xenc   = ws + 1163392;      // 2,228,224
    bf16*  Xbf    = (bf16*)(ws + 3391616);       // 2,228,224 bf16
    bf16*  Abf    = (bf16*)(ws + 4505728);       // 2,228,224 bf16
    bf16*  Hbf    = (bf16*)(ws + 5619840);       // 8,912,896 bf16
    bf16*  QKVbf  = (bf16*)(ws + 10076288);      // 6,684,672 bf16
    float* O2     = ws + 13418624;     // 2,228,224
    float* SE     = ws + 15646848;     // 2,228,224 (ends 17,875,072 f = 68.2 MiB)

    // bf16 weight sub-arena
    bf16* wbf_aw  = wbf;               // 8 mats of 256x256 -> (2048,256)
    bf16* wbf_fw1 = wbf + 524288;      // (2048,256)
    bf16* wbf_fw2 = wbf + 1048576;     // (512,1024)
    bf16* wbf_wca = wbf + 1572864;     // (1024,256)
    bf16* wbf_gcn = wbf + 1835008;     // (128,128)

    // phase aliases
    float* Xg   = O2;                  // GCN input f32 (16000x128)
    bf16*  Xgbf = Hbf;                 // GCN input bf16
    float* Eg   = SE;                  // GCN output (16000x128)
    bf16*  Qwbf = QKVbf;               // WCA Q bf16 (8192x256)
    bf16*  KVbf = QKVbf + 4194304;     // WCA KV bf16 (512x512)

    // --- weight convert+transpose (f32 -> bf16 (N,K)) ---
    k_transp<<<dim3(8, 8, 8),  dim3(32, 8), 0, stream>>>(aw,    wbf_aw, 256, 256);
    k_transp<<<dim3(32, 8, 2), dim3(32, 8), 0, stream>>>(fw1,   wbf_fw1, 256, 1024);
    k_transp<<<dim3(8, 32, 2), dim3(32, 8), 0, stream>>>(fw2,   wbf_fw2, 1024, 256);
    k_transp<<<dim3(8, 8, 4),  dim3(32, 8), 0, stream>>>(wca_w, wbf_wca, 256, 256);
    k_transp<<<dim3(4, 4, 1),  dim3(32, 8), 0, stream>>>(gcn_w, wbf_gcn, 128, 128);

    // --- graph + GCN (sparse) ---
    hipMemsetAsync(dvec, 0, 16000 * sizeof(float), stream);
    k_colsum<<<(NEDGE + 255) / 256, 256, 0, stream>>>(history, dvec);
    k_dsqrt<<<(B_N * C_N + 255) / 256, 256, 0, stream>>>(dvec);
    k_initX<<<B_N * C_N * DIMN / 256, 256, 0, stream>>>(dvec, emb, Xg);
    k_edgeX<<<NEDGE, 128, 0, stream>>>(history, dvec, emb, Xg);
    k_tobf<<<2000, 256, 0, stream>>>(Xg, Xgbf, B_N * C_N * DIMN);
    k_bgemm<2><<<dim3(2, 125), 256, 0, stream>>>(Xgbf, wbf_gcn, gcn_b, nullptr, Eg,
                                                 B_N * C_N, DIMN, DIMN);

    // --- fuse ---
    k_temp<<<S_N, DM, 0, stream>>>(temp);
    k_fuse<<<NSEQ * S_N, DM, 0, stream>>>(history, cur, emb, Eg, nullE, temp, Xenc, Xbf, maskb);

    // --- encoder, L=2 ---
    for (int l = 0; l < 2; ++l) {
        k_bgemm<9><<<dim3(12, 68), 256, 0, stream>>>(Xbf, wbf_aw + l * 262144,
                ab + l * 1024, nullptr, QKVbf, NSEQ * S_N, 768, 256);
        k_mattn<false><<<NSEQ * 4, 64, 0, stream>>>(QKVbf, QKVbf + 256, QKVbf + 512,
                maskb, Abf, 768, 768);
        k_bgemm<0><<<dim3(4, 68), 256, 0, stream>>>(Abf, wbf_aw + l * 262144 + 196608,
                ab + l * 1024 + 768, nullptr, O2, NSEQ * S_N, 256, 256);
        k_ln<<<NSEQ * S_N, DM, 0, stream>>>(Xenc, O2, lns + (l * 2 + 0) * DM, lnb + (l * 2 + 0) * DM, Xbf);
        k_bgemm<10><<<dim3(16, 68), 256, 0, stream>>>(Xbf, wbf_fw1 + l * 262144,
                fb1 + l * DFF, nullptr, Hbf, NSEQ * S_N, DFF, 256);
        k_bgemm<0><<<dim3(4, 68), 256, 0, stream>>>(Hbf, wbf_fw2 + l * 262144,
                fb2 + l * DM, nullptr, O2, NSEQ * S_N, 256, 1024);
        k_ln<<<NSEQ * S_N, DM, 0, stream>>>(Xenc, O2, lns + (l * 2 + 1) * DM, lnb + (l * 2 + 1) * DM, Xbf);
    }

    float* mh = Xenc;                            // 128 seqs f32
    bf16*  mc_bf = Xbf + (size_t)128 * S_N * DM; // 8 seqs bf16

    // --- windowed cross attention ---
    k_bgemm<9><<<dim3(4, 64), 256, 0, stream>>>(Xbf, wbf_wca, wca_b, nullptr, Qwbf,
                                                128 * S_N, 256, 256);
    k_bgemm<9><<<dim3(8, 4), 256, 0, stream>>>(mc_bf, wbf_wca + 65536, wca_b + 256, nullptr, KVbf,
                                               B_N * S_N, 512, 256);
    k_mattn<true><<<128 * 4, 64, 0, stream>>>(Qwbf, KVbf, KVbf + 256, nullptr, Abf, 256, 512);
    k_bgemm<4><<<dim3(4, 64), 256, 0, stream>>>(Abf, wbf_wca + 196608, wca_b + 768, mh, SE,
                                                128 * S_N, 256, 256);

    // --- aggregate + final (fp32 tail for accuracy) ---
    k_agg<<<B_N * S_N, DM, 0, stream>>>(SE, Xenc + (size_t)128 * S_N * DM, aggmc);
    k_gemm<3, false><<<dim3(2, 8), 256, 0, stream>>>(aggmc, ial_w, ial_b, nullptr, finalb,
                                                     B_N * S_N, DIMN, DM);
    k_gemm<0, true><<<dim3(32, 8), 256, 0, stream>>>(finalb, emb, nullptr, nullptr, out,
                                                     B_N * S_N, C_N, DIMN);
}

// Round 5
// 347.525 us; speedup vs baseline: 3.6358x; 1.0951x over previous
//
#include <hip/hip_runtime.h>
#include <hip/hip_bf16.h>
#include <math.h>

#define C_N   2000
#define DIMN  128
#define DM    256
#define B_N   8
#define HT    16
#define S_N   64
#define NSEQ  136
#define DFF   1024
#define NEDGE (B_N*HT*(S_N-1))   // 8064

typedef __hip_bfloat16 bf16;
typedef short bf16x8 __attribute__((ext_vector_type(8)));
typedef float f32x4  __attribute__((ext_vector_type(4)));

#define GLOAD_LDS16(gp, lp) \
    __builtin_amdgcn_global_load_lds((const __attribute__((address_space(1))) void*)(gp), \
                                     (__attribute__((address_space(3))) void*)(lp), 16, 0, 0)

__device__ __forceinline__ short f2bf(float v) {
    bf16 t = (bf16)v;
    return *reinterpret_cast<short*>(&t);
}

// ---------------- graph / GCN ----------------

__global__ void k_colsum(const int* __restrict__ hist, float* __restrict__ colsum) {
    int e = blockIdx.x * blockDim.x + threadIdx.x;
    if (e >= NEDGE) return;
    int s = e % (S_N-1); int bh = e / (S_N-1); int h = bh % HT; int b = bh / HT;
    const int* row = hist + (size_t)bh * S_N;
    int src = row[s], dst = row[s+1];
    if (src != C_N && dst != C_N && src != dst) {
        float w = 1.f + expf(-0.01f * (float)(HT - 1 - h));
        atomicAdd(&colsum[b * C_N + dst], w);
    }
}

// Eg[b,c,:] = dd^2 * Y[c,:] + gcn_b   (dd = sqrt(1+colsum))
__global__ void k_initX(const float* __restrict__ cs, const float* __restrict__ Y,
                        const float* __restrict__ gb, float* __restrict__ Eg) {
    size_t i = (size_t)blockIdx.x * 256 + threadIdx.x;   // over B*C*DIM
    int k = (int)(i % DIMN); size_t bc = i / DIMN;
    int c = (int)(bc % C_N); int b = (int)(bc / C_N);
    float dd2 = 1.f + cs[b * C_N + c];
    Eg[i] = dd2 * Y[(size_t)c * DIMN + k] + gb[k];
}

__global__ void k_edgeX(const int* __restrict__ hist, const float* __restrict__ cs,
                        const float* __restrict__ Y, float* __restrict__ Eg) {
    int e = blockIdx.x;
    int s = e % (S_N-1); int bh = e / (S_N-1); int h = bh % HT; int b = bh / HT;
    const int* row = hist + (size_t)bh * S_N;
    int src = row[s], dst = row[s+1];
    if (src == C_N || dst == C_N || src == dst) return;
    float w = (1.f + expf(-0.01f * (float)(HT - 1 - h)))
            * sqrtf(1.f + cs[b*C_N+src]) * sqrtf(1.f + cs[b*C_N+dst]);
    int k = threadIdx.x;  // 128
    atomicAdd(&Eg[((size_t)b * C_N + src) * DIMN + k], w * Y[(size_t)dst * DIMN + k]);
}

// ---------------- fp32 -> bf16 convert (emb) ----------------

__global__ void k_tobf(const float* __restrict__ s, bf16* __restrict__ d, int n) {
    int i = (blockIdx.x * 256 + threadIdx.x) * 4;
    if (i >= n) return;
    float4 v = *(const float4*)(s + i);
    d[i]   = (bf16)v.x; d[i+1] = (bf16)v.y; d[i+2] = (bf16)v.z; d[i+3] = (bf16)v.w;
}

// ---------------- consolidated weight transpose+convert ----------------
// each entry: nm matrices of (K,N) f32 -> (nm*N, K) bf16
struct TEnt { const float* s; bf16* d; int K; int N; int nm; int tiles; };
struct TPack { TEnt e[6]; };

__global__ void k_wtpack(TPack p) {
    __shared__ float t[32][33];
    int id = blockIdx.x;
    TEnt en = p.e[0];
    #pragma unroll
    for (int k = 0; k < 6; ++k) {
        if (id < p.e[k].tiles) { en = p.e[k]; break; }
        id -= p.e[k].tiles;
    }
    int tn = en.N >> 5;
    int per = (en.K >> 5) * tn;
    int mat = id / per, t2 = id % per;
    int ty = t2 / tn, tx = t2 % tn;
    const float* s = en.s + (size_t)mat * en.K * en.N;
    bf16* d = en.d + (size_t)mat * en.N * en.K;
    int k0 = ty * 32, n0 = tx * 32;
    #pragma unroll
    for (int j = 0; j < 32; j += 8)
        t[threadIdx.y + j][threadIdx.x] = s[(size_t)(k0 + threadIdx.y + j) * en.N + n0 + threadIdx.x];
    __syncthreads();
    #pragma unroll
    for (int j = 0; j < 32; j += 8)
        d[(size_t)(n0 + threadIdx.y + j) * en.K + k0 + threadIdx.x] = (bf16)t[threadIdx.x][threadIdx.y + j];
}

// ---------------- bf16 MFMA GEMM ----------------
// C[M,N] = epi(A[M,K] @ Bt[N,K]^T), EPI bits: 1=bias, 2=relu, 4=resid(f32,ldc),
// 8=bf16 out, 16=col-mask(col<nreal). Requires M%128==0, N%64==0, K%64==0.
template<int EPI>
__global__ __launch_bounds__(256) void k_bgemm(
        const bf16* __restrict__ A, const bf16* __restrict__ Bt,
        const float* __restrict__ bias, const float* __restrict__ resid,
        void* __restrict__ Cout, int M, int N, int K, int ldc, int nreal)
{
    __shared__ bf16 As[128 * 64];
    __shared__ bf16 Bs[64 * 64];
    int tid = threadIdx.x;
    int wid = tid >> 6, lane = tid & 63;
    int m0 = blockIdx.y * 128, n0 = blockIdx.x * 64;
    int wr = wid >> 1, wc = wid & 1;        // wave sub-tile: 64 rows x 32 cols
    int lr = lane >> 3, lc = lane & 7;
    int gc = lc ^ lr;                       // pre-swizzled global chunk (16B units)
    f32x4 acc[4][2] = {};

    int nkt = K >> 6;
    for (int kt = 0; kt < nkt; ++kt) {
        int kb = kt << 6;
        #pragma unroll
        for (int s = 0; s < 4; ++s) {       // A: 16 segs of 8 rows; 4 per wave
            int seg = wid * 4 + s;
            int row = seg * 8 + lr;
            GLOAD_LDS16(A + (size_t)(m0 + row) * K + kb + gc * 8, As + seg * 512);
        }
        #pragma unroll
        for (int s = 0; s < 2; ++s) {       // B: 8 segs; 2 per wave
            int seg = wid * 2 + s;
            int row = seg * 8 + lr;
            GLOAD_LDS16(Bt + (size_t)(n0 + row) * K + kb + gc * 8, Bs + seg * 512);
        }
        __syncthreads();
        #pragma unroll
        for (int kk = 0; kk < 2; ++kk) {
            bf16x8 af[4], bfr[2];
            int c = kk * 4 + (lane >> 4);
            #pragma unroll
            for (int m = 0; m < 4; ++m) {
                int row = wr * 64 + m * 16 + (lane & 15);
                af[m] = *(const bf16x8*)(As + row * 64 + (c ^ (row & 7)) * 8);
            }
            #pragma unroll
            for (int n = 0; n < 2; ++n) {
                int row = wc * 32 + n * 16 + (lane & 15);
                bfr[n] = *(const bf16x8*)(Bs + row * 64 + (c ^ (row & 7)) * 8);
            }
            #pragma unroll
            for (int m = 0; m < 4; ++m)
                #pragma unroll
                for (int n = 0; n < 2; ++n)
                    acc[m][n] = __builtin_amdgcn_mfma_f32_16x16x32_bf16(af[m], bfr[n], acc[m][n], 0, 0, 0);
        }
        __syncthreads();
    }
    int cl = lane & 15, ch = lane >> 4;
    #pragma unroll
    for (int n = 0; n < 2; ++n) {
        int col = n0 + wc * 32 + n * 16 + cl;
        if ((EPI & 16) && col >= nreal) continue;
        float bv = (EPI & 1) ? bias[col] : 0.f;
        #pragma unroll
        for (int m = 0; m < 4; ++m) {
            #pragma unroll
            for (int j = 0; j < 4; ++j) {
                int row = m0 + wr * 64 + m * 16 + ch * 4 + j;
                float v = acc[m][n][j] + bv;
                if (EPI & 4) v += resid[(size_t)row * ldc + col];
                if (EPI & 2) v = fmaxf(v, 0.f);
                if (EPI & 8) ((bf16*)Cout)[(size_t)row * ldc + col] = (bf16)v;
                else         ((float*)Cout)[(size_t)row * ldc + col] = v;
            }
        }
    }
}

// ---------------- bf16 MFMA GEMM + residual + LayerNorm fused ----------------
// Xf (f32, [M,256]): resid in, LN result out (in place). Xb: bf16 copy out.
// tile: BM=64 x N=256 (full row), BK=64, 256 threads (4 waves, one col-quarter each).
__global__ __launch_bounds__(256) void k_bgemm_ln(
        const bf16* __restrict__ A, const bf16* __restrict__ Bt,
        const float* __restrict__ bias, float* __restrict__ Xf,
        const float* __restrict__ lns_, const float* __restrict__ lnb_,
        bf16* __restrict__ Xb, int M, int K)
{
    __shared__ bf16 As[64 * 64];
    __shared__ bf16 Bs[256 * 64];
    __shared__ float ls1[64][4], ls2[64][4];
    int tid = threadIdx.x, wid = tid >> 6, lane = tid & 63;
    int lr = lane >> 3, lc = lane & 7, gc = lc ^ lr;
    int cl = lane & 15, ch = lane >> 4;
    int m0 = blockIdx.x * 64;
    int wc = wid;                           // col quarter 0..3
    f32x4 acc[4][4] = {};
    int nkt = K >> 6;
    for (int kt = 0; kt < nkt; ++kt) {
        int kb = kt << 6;
        #pragma unroll
        for (int s = 0; s < 2; ++s) {       // A: 8 segs, 2/wave
            int seg = wid * 2 + s, row = seg * 8 + lr;
            GLOAD_LDS16(A + (size_t)(m0 + row) * K + kb + gc * 8, As + seg * 512);
        }
        #pragma unroll
        for (int s = 0; s < 8; ++s) {       // B: 32 segs, 8/wave
            int seg = wid * 8 + s, row = seg * 8 + lr;
            GLOAD_LDS16(Bt + (size_t)row * K + kb + gc * 8, Bs + seg * 512);
        }
        __syncthreads();
        #pragma unroll
        for (int kk = 0; kk < 2; ++kk) {
            int c = kk * 4 + ch;
            bf16x8 af[4], bfr[4];
            #pragma unroll
            for (int m = 0; m < 4; ++m) {
                int row = m * 16 + cl;
                af[m] = *(const bf16x8*)(As + row * 64 + (c ^ (row & 7)) * 8);
            }
            #pragma unroll
            for (int n = 0; n < 4; ++n) {
                int row = wc * 64 + n * 16 + cl;
                bfr[n] = *(const bf16x8*)(Bs + row * 64 + (c ^ (row & 7)) * 8);
            }
            #pragma unroll
            for (int m = 0; m < 4; ++m)
                #pragma unroll
                for (int n = 0; n < 4; ++n)
                    acc[m][n] = __builtin_amdgcn_mfma_f32_16x16x32_bf16(af[m], bfr[n], acc[m][n], 0, 0, 0);
        }
        __syncthreads();
    }
    // pass 1: v = acc + bias + resid; row partial sums
    #pragma unroll
    for (int m = 0; m < 4; ++m) {
        #pragma unroll
        for (int j = 0; j < 4; ++j) {
            int rl = m * 16 + ch * 4 + j;
            float s1 = 0.f, s2 = 0.f;
            #pragma unroll
            for (int n = 0; n < 4; ++n) {
                int col = wc * 64 + n * 16 + cl;
                float v = acc[m][n][j] + bias[col] + Xf[(size_t)(m0 + rl) * 256 + col];
                acc[m][n][j] = v;
                s1 += v; s2 += v * v;
            }
            s1 += __shfl_xor(s1, 1); s2 += __shfl_xor(s2, 1);
            s1 += __shfl_xor(s1, 2); s2 += __shfl_xor(s2, 2);
            s1 += __shfl_xor(s1, 4); s2 += __shfl_xor(s2, 4);
            s1 += __shfl_xor(s1, 8); s2 += __shfl_xor(s2, 8);
            if (cl == 0) { ls1[rl][wc] = s1; ls2[rl][wc] = s2; }
        }
    }
    __syncthreads();
    // pass 2: normalize + write
    #pragma unroll
    for (int m = 0; m < 4; ++m) {
        #pragma unroll
        for (int j = 0; j < 4; ++j) {
            int rl = m * 16 + ch * 4 + j;
            float su = ls1[rl][0] + ls1[rl][1] + ls1[rl][2] + ls1[rl][3];
            float sq = ls2[rl][0] + ls2[rl][1] + ls2[rl][2] + ls2[rl][3];
            float mean = su * (1.f / 256.f);
            float var  = sq * (1.f / 256.f) - mean * mean;
            float rstd = rsqrtf(var + 1e-5f);
            #pragma unroll
            for (int n = 0; n < 4; ++n) {
                int col = wc * 64 + n * 16 + cl;
                float r = (acc[m][n][j] - mean) * rstd * lns_[col] + lnb_[col];
                size_t g = (size_t)(m0 + rl) * 256 + col;
                Xf[g] = r;
                Xb[g] = (bf16)r;
            }
        }
    }
}

// ---------------- temporal encoding + fuse ----------------

__global__ void k_temp(float* __restrict__ temp) {
    int s = blockIdx.x; int d = threadIdx.x;
    int k = d >> 1;
    float den = powf(10000.f, (2.f * (float)k) / 256.f);
    float arg = (float)s / den;
    temp[s * DM + d] = (d & 1) ? cosf(arg) : sinf(arg);
}

__global__ void k_fuse(const int* __restrict__ hist, const int* __restrict__ cur,
                       const float* __restrict__ E, const float* __restrict__ Eg,
                       const float* __restrict__ nullE, const float* __restrict__ temp,
                       float* __restrict__ Xenc, bf16* __restrict__ Xbf,
                       float* __restrict__ maskb) {
    int blk = blockIdx.x;           // seq*64 + s
    int seq = blk >> 6, s = blk & 63;
    int d = threadIdx.x;
    int idx, b;
    if (seq < 128) { b = seq >> 4; idx = hist[(size_t)seq * S_N + s]; }
    else           { b = seq - 128; idx = cur[b * S_N + s]; }
    float t = temp[s * DM + d];
    float v;
    if (idx == C_N) v = nullE[d] + t;
    else {
        v = ((d < DIMN) ? E[(size_t)idx * DIMN + d]
                        : fmaxf(Eg[((size_t)b * C_N + idx) * DIMN + (d - DIMN)], 0.f)) + t;
    }
    size_t o = ((size_t)seq * S_N + s) * DM + d;
    Xenc[o] = v;
    Xbf[o]  = (bf16)v;
    if (d == 0) maskb[seq * S_N + s] = (idx == C_N) ? -INFINITY : 0.f;
}

// ---------------- MFMA attention: one wave per (seq, head) ----------------
template<bool WCA>
__global__ __launch_bounds__(64) void k_mattn(
        const bf16* __restrict__ Qb, const bf16* __restrict__ Kb,
        const bf16* __restrict__ Vb, const float* __restrict__ maskb,
        bf16* __restrict__ O, int qstr, int kstr)
{
    int seq = blockIdx.x >> 2, head = blockIdx.x & 3;
    int lane = threadIdx.x;
    int cl = lane & 15, ch = lane >> 4;
    __shared__ __align__(16) short VT[64 * 72];   // V^T [d][k]
    __shared__ __align__(16) short PT[64 * 72];   // P [q][k]; later O staging

    const bf16* Qp = Qb + (size_t)seq * 64 * qstr + head * 64;
    int kvseq = WCA ? (seq >> 4) : seq;
    const bf16* Kp = Kb + (size_t)kvseq * 64 * kstr + head * 64;
    const bf16* Vp = Vb + (size_t)kvseq * 64 * kstr + head * 64;

    bf16x8 aq[4][2], bk[4][2], vr[4][2];
    #pragma unroll
    for (int t = 0; t < 4; ++t)
        #pragma unroll
        for (int kk = 0; kk < 2; ++kk) {
            int row = t * 16 + cl, d0 = kk * 32 + ch * 8;
            aq[t][kk] = *(const bf16x8*)(Qp + (size_t)row * qstr + d0);
            bk[t][kk] = *(const bf16x8*)(Kp + (size_t)row * kstr + d0);
            vr[t][kk] = *(const bf16x8*)(Vp + (size_t)row * kstr + d0);
        }

    f32x4 sa[4][4] = {};
    #pragma unroll
    for (int kk = 0; kk < 2; ++kk)
        #pragma unroll
        for (int m = 0; m < 4; ++m)
            #pragma unroll
            for (int n = 0; n < 4; ++n)
                sa[m][n] = __builtin_amdgcn_mfma_f32_16x16x32_bf16(aq[m][kk], bk[n][kk], sa[m][n], 0, 0, 0);

    #pragma unroll
    for (int t = 0; t < 4; ++t)
        #pragma unroll
        for (int kk = 0; kk < 2; ++kk) {
            int k = t * 16 + cl, d0 = kk * 32 + ch * 8;
            #pragma unroll
            for (int e = 0; e < 8; ++e)
                VT[(d0 + e) * 72 + k] = vr[t][kk][e];
        }

    float mk4[4];
    if (!WCA) {
        #pragma unroll
        for (int n = 0; n < 4; ++n) mk4[n] = maskb[seq * 64 + n * 16 + cl];
    }

    #pragma unroll
    for (int m = 0; m < 4; ++m) {
        #pragma unroll
        for (int j = 0; j < 4; ++j) {
            int q = m * 16 + ch * 4 + j;
            float rm = -INFINITY;
            #pragma unroll
            for (int n = 0; n < 4; ++n) {
                int k = n * 16 + cl;
                float msk = WCA ? ((abs(q - k) <= 4) ? 0.f : -INFINITY) : mk4[n];
                float v = sa[m][n][j] * 0.125f + msk;
                sa[m][n][j] = v;
                rm = fmaxf(rm, v);
            }
            rm = fmaxf(rm, __shfl_xor(rm, 1));
            rm = fmaxf(rm, __shfl_xor(rm, 2));
            rm = fmaxf(rm, __shfl_xor(rm, 4));
            rm = fmaxf(rm, __shfl_xor(rm, 8));
            float rs = 0.f;
            #pragma unroll
            for (int n = 0; n < 4; ++n) {
                float e = expf(sa[m][n][j] - rm);
                sa[m][n][j] = e;
                rs += e;
            }
            rs += __shfl_xor(rs, 1);
            rs += __shfl_xor(rs, 2);
            rs += __shfl_xor(rs, 4);
            rs += __shfl_xor(rs, 8);
            float inv = 1.f / rs;
            #pragma unroll
            for (int n = 0; n < 4; ++n)
                PT[q * 72 + n * 16 + cl] = f2bf(sa[m][n][j] * inv);
        }
    }
    __syncthreads();

    f32x4 oa[4][4] = {};
    #pragma unroll
    for (int kk = 0; kk < 2; ++kk) {
        bf16x8 av[4], bp[4];
        #pragma unroll
        for (int dm = 0; dm < 4; ++dm)
            av[dm] = *(const bf16x8*)(VT + (dm * 16 + cl) * 72 + kk * 32 + ch * 8);
        #pragma unroll
        for (int qn = 0; qn < 4; ++qn)
            bp[qn] = *(const bf16x8*)(PT + (qn * 16 + cl) * 72 + kk * 32 + ch * 8);
        #pragma unroll
        for (int dm = 0; dm < 4; ++dm)
            #pragma unroll
            for (int qn = 0; qn < 4; ++qn)
                oa[dm][qn] = __builtin_amdgcn_mfma_f32_16x16x32_bf16(av[dm], bp[qn], oa[dm][qn], 0, 0, 0);
    }
    __syncthreads();

    #pragma unroll
    for (int dm = 0; dm < 4; ++dm)
        #pragma unroll
        for (int qn = 0; qn < 4; ++qn)
            #pragma unroll
            for (int j = 0; j < 4; ++j)
                PT[(qn * 16 + cl) * 72 + dm * 16 + ch * 4 + j] = f2bf(oa[dm][qn][j]);
    __syncthreads();
    #pragma unroll
    for (int it = 0; it < 8; ++it) {       // 512 chunks of 8 bf16
        int chunk = it * 64 + lane;
        int tok = chunk >> 3, d0 = (chunk & 7) * 8;
        bf16x8 v = *(const bf16x8*)(PT + tok * 72 + d0);
        *(bf16x8*)(O + ((size_t)seq * 64 + tok) * 256 + head * 64 + d0) = v;
    }
}

// ---------------- scores + softmax-over-h + aggregate (bf16 out) ----------------

__global__ __launch_bounds__(256) void k_agg(const float* __restrict__ wca,
                                             const float* __restrict__ mc,
                                             bf16* __restrict__ aggbf) {
    int bs = blockIdx.x; int b = bs >> 6, s = bs & 63;
    int d = threadIdx.x;
    __shared__ float red[4][16];
    float mcv = mc[((size_t)b * S_N + s) * DM + d];
    float wv[16], p[16];
    #pragma unroll
    for (int h = 0; h < 16; ++h) {
        wv[h] = wca[(((size_t)(b * HT + h)) * S_N + s) * DM + d];
        p[h] = wv[h] * mcv;
    }
    #pragma unroll
    for (int o = 1; o < 64; o <<= 1)
        #pragma unroll
        for (int h = 0; h < 16; ++h) p[h] += __shfl_xor(p[h], o);
    if ((d & 63) == 0) {
        int w = d >> 6;
        #pragma unroll
        for (int h = 0; h < 16; ++h) red[w][h] = p[h];
    }
    __syncthreads();
    float sc[16], mx = -INFINITY;
    #pragma unroll
    for (int h = 0; h < 16; ++h) {
        sc[h] = (red[0][h] + red[1][h] + red[2][h] + red[3][h]) * (1.f / 16.f);
        mx = fmaxf(mx, sc[h]);
    }
    float e[16], sum = 0.f;
    #pragma unroll
    for (int h = 0; h < 16; ++h) { e[h] = expf(sc[h] - mx); sum += e[h]; }
    float inv = 1.f / sum;
    float acc = 0.f;
    #pragma unroll
    for (int h = 0; h < 16; ++h) acc += e[h] * inv * wv[h];
    aggbf[((size_t)b * S_N + s) * DM + d] = (bf16)(acc + mcv);
}

// ---------------- launch ----------------

extern "C" void kernel_launch(void* const* d_in, const int* in_sizes, int n_in,
                              void* d_out, int out_size, void* d_ws, size_t ws_size,
                              hipStream_t stream) {
    const int*   history = (const int*)d_in[0];
    const int*   cur     = (const int*)d_in[1];
    const float* emb     = (const float*)d_in[2];
    const float* nullE   = (const float*)d_in[3];
    const float* gcn_w   = (const float*)d_in[4];
    const float* gcn_b   = (const float*)d_in[5];
    const float* aw      = (const float*)d_in[6];
    const float* ab      = (const float*)d_in[7];
    const float* fw1     = (const float*)d_in[8];
    const float* fb1     = (const float*)d_in[9];
    const float* fw2     = (const float*)d_in[10];
    const float* fb2     = (const float*)d_in[11];
    const float* lns     = (const float*)d_in[12];
    const float* lnb     = (const float*)d_in[13];
    const float* wca_w   = (const float*)d_in[14];
    const float* wca_b   = (const float*)d_in[15];
    const float* ial_w   = (const float*)d_in[16];
    const float* ial_b   = (const float*)d_in[17];
    float* out = (float*)d_out;
    float* ws  = (float*)d_ws;

    // ---- arena (float offsets) ----
    float* dvec   = ws + 0;            // 16,000  (colsum)
    float* maskb  = ws + 16000;        // 8,704
    float* temp   = ws + 24704;        // 16,384
    bf16*  aggbf  = (bf16*)(ws + 41088);         // 131,072 bf16 (512x256)
    bf16*  finalb = (bf16*)(ws + 106624);        // 65,536 bf16 (512x128)
    bf16*  embbf  = (bf16*)(ws + 139392);        // 262,144 bf16 (2048x128, padded)
    float* Y      = ws + 270464;       // 262,144 f32 (2048x128)
    float* Eg     = ws + 532608;       // 2,048,000 f32 (8x2000x128)
    bf16*  wbf    = (bf16*)(ws + 2580608);       // 1,884,160 bf16
    float* Xenc   = ws + 3522688;      // 2,228,224 f32
    bf16*  Xbf    = (bf16*)(ws + 5750912);       // 2,228,224 bf16
    bf16*  Abf    = (bf16*)(ws + 6865024);       // 2,228,224 bf16
    bf16*  Hbf    = (bf16*)(ws + 7979136);       // 8,912,896 bf16
    bf16*  QKVbf  = (bf16*)(ws + 12435584);      // 6,684,672 bf16
    float* SE     = ws + 15777920;     // 2,097,152 f32 (ends 17,875,072 f = 71.5 MiB)

    // bf16 weight sub-arena
    bf16* wbf_aw  = wbf;               // 8 x (256,256)
    bf16* wbf_fw1 = wbf + 524288;      // 2 x (1024,256)
    bf16* wbf_fw2 = wbf + 1048576;     // 2 x (256,1024)
    bf16* wbf_wca = wbf + 1572864;     // 4 x (256,256)
    bf16* wbf_gcn = wbf + 1835008;     // (128,128)
    bf16* wbf_ial = wbf + 1851392;     // (128,256)

    // aliases (QKV region reused for WCA)
    bf16* Qwbf = QKVbf;                // 8192x256
    bf16* KVbf = QKVbf + 4194304;      // 512x512

    // --- weight pack: all transposes in one kernel ---
    TPack tp;
    tp.e[0] = { aw,    wbf_aw,  256,  256, 8, 512 };
    tp.e[1] = { fw1,   wbf_fw1, 256, 1024, 2, 512 };
    tp.e[2] = { fw2,   wbf_fw2, 1024, 256, 2, 512 };
    tp.e[3] = { wca_w, wbf_wca, 256,  256, 4, 256 };
    tp.e[4] = { gcn_w, wbf_gcn, 128,  128, 1,  16 };
    tp.e[5] = { ial_w, wbf_ial, 256,  128, 1,  32 };
    k_wtpack<<<1840, dim3(32, 8), 0, stream>>>(tp);

    // --- emb -> bf16 (padded to 2048 rows) ---
    hipMemsetAsync(embbf + 2000 * 128, 0, 48 * 128 * sizeof(bf16), stream);
    k_tobf<<<250, 256, 0, stream>>>(emb, embbf, C_N * DIMN);

    // --- graph + GCN:  A'(E@W) via Y = E@W then sparse scatter ---
    hipMemsetAsync(dvec, 0, 16000 * sizeof(float), stream);
    k_colsum<<<(NEDGE + 255) / 256, 256, 0, stream>>>(history, dvec);
    k_bgemm<0><<<dim3(2, 16), 256, 0, stream>>>(embbf, wbf_gcn, nullptr, nullptr, Y,
                                                2048, DIMN, DIMN, DIMN, DIMN);
    k_initX<<<B_N * C_N * DIMN / 256, 256, 0, stream>>>(dvec, Y, gcn_b, Eg);
    k_edgeX<<<NEDGE, 128, 0, stream>>>(history, dvec, Y, Eg);

    // --- fuse (relu(Eg) folded in) ---
    k_temp<<<S_N, DM, 0, stream>>>(temp);
    k_fuse<<<NSEQ * S_N, DM, 0, stream>>>(history, cur, emb, Eg, nullE, temp, Xenc, Xbf, maskb);

    // --- encoder, L=2 ---
    for (int l = 0; l < 2; ++l) {
        k_bgemm<9><<<dim3(12, 68), 256, 0, stream>>>(Xbf, wbf_aw + l * 262144,
                ab + l * 1024, nullptr, QKVbf, NSEQ * S_N, 768, 256, 768, 768);
        k_mattn<false><<<NSEQ * 4, 64, 0, stream>>>(QKVbf, QKVbf + 256, QKVbf + 512,
                maskb, Abf, 768, 768);
        k_bgemm_ln<<<NSEQ, 256, 0, stream>>>(Abf, wbf_aw + l * 262144 + 196608,
                ab + l * 1024 + 768, Xenc, lns + (l * 2 + 0) * DM, lnb + (l * 2 + 0) * DM,
                Xbf, NSEQ * S_N, 256);
        k_bgemm<11><<<dim3(16, 68), 256, 0, stream>>>(Xbf, wbf_fw1 + l * 262144,
                fb1 + l * DFF, nullptr, Hbf, NSEQ * S_N, DFF, 256, DFF, DFF);
        k_bgemm_ln<<<NSEQ, 256, 0, stream>>>(Hbf, wbf_fw2 + l * 262144,
                fb2 + l * DM, Xenc, lns + (l * 2 + 1) * DM, lnb + (l * 2 + 1) * DM,
                Xbf, NSEQ * S_N, 1024);
    }

    float* mh = Xenc;                            // 128 seqs f32
    bf16*  mc_bf = Xbf + (size_t)128 * S_N * DM; // 8 seqs bf16

    // --- windowed cross attention ---
    k_bgemm<9><<<dim3(4, 64), 256, 0, stream>>>(Xbf, wbf_wca, wca_b, nullptr, Qwbf,
                                                128 * S_N, 256, 256, 256, 256);
    k_bgemm<9><<<dim3(8, 4), 256, 0, stream>>>(mc_bf, wbf_wca + 65536, wca_b + 256, nullptr,
                                               KVbf, B_N * S_N, 512, 256, 512, 512);
    k_mattn<true><<<128 * 4, 64, 0, stream>>>(Qwbf, KVbf, KVbf + 256, nullptr, Abf, 256, 512);
    k_bgemm<5><<<dim3(4, 64), 256, 0, stream>>>(Abf, wbf_wca + 196608, wca_b + 768, mh, SE,
                                                128 * S_N, 256, 256, 256, 256);

    // --- aggregate + final (bf16 MFMA tail) ---
    k_agg<<<B_N * S_N, 256, 0, stream>>>(SE, Xenc + (size_t)128 * S_N * DM, aggbf);
    k_bgemm<11><<<dim3(2, 4), 256, 0, stream>>>(aggbf, wbf_ial, ial_b, nullptr, finalb,
                                                B_N * S_N, DIMN, DM, DIMN, DIMN);
    k_bgemm<16><<<dim3(32, 4), 256, 0, stream>>>(finalb, embbf, nullptr, nullptr, out,
                                                 B_N * S_N, 2048, DIMN, C_N, C_N);
}

// Round 6
// 320.690 us; speedup vs baseline: 3.9400x; 1.0837x over previous
//
#include <hip/hip_runtime.h>
#include <hip/hip_bf16.h>
#include <math.h>

#define C_N   2000
#define DIMN  128
#define DM    256
#define B_N   8
#define HT    16
#define S_N   64
#define NSEQ  136
#define DFF   1024
#define NEDGE (B_N*HT*(S_N-1))   // 8064

typedef __hip_bfloat16 bf16;
typedef short bf16x8 __attribute__((ext_vector_type(8)));
typedef float f32x4  __attribute__((ext_vector_type(4)));

#define GLOAD_LDS16(gp, lp) \
    __builtin_amdgcn_global_load_lds((const __attribute__((address_space(1))) void*)(gp), \
                                     (__attribute__((address_space(3))) void*)(lp), 16, 0, 0)

__device__ __forceinline__ short f2bf(float v) {
    bf16 t = (bf16)v;
    return *reinterpret_cast<short*>(&t);
}

// ---------------- graph / GCN ----------------

// Eg[b,c,:] = dd^2 * Y[c,:] + gcn_b   (dd^2 = 1+colsum)
__global__ void k_initX(const float* __restrict__ cs, const float* __restrict__ Y,
                        const float* __restrict__ gb, float* __restrict__ Eg) {
    size_t i = (size_t)blockIdx.x * 256 + threadIdx.x;   // over B*C*DIM
    int k = (int)(i % DIMN); size_t bc = i / DIMN;
    int c = (int)(bc % C_N); int b = (int)(bc / C_N);
    float dd2 = 1.f + cs[b * C_N + c];
    Eg[i] = dd2 * Y[(size_t)c * DIMN + k] + gb[k];
}

__global__ void k_edgeX(const int* __restrict__ hist, const float* __restrict__ cs,
                        const float* __restrict__ Y, float* __restrict__ Eg) {
    int e = blockIdx.x;
    int s = e % (S_N-1); int bh = e / (S_N-1); int h = bh % HT; int b = bh / HT;
    const int* row = hist + (size_t)bh * S_N;
    int src = row[s], dst = row[s+1];
    if (src == C_N || dst == C_N || src == dst) return;
    float w = (1.f + expf(-0.01f * (float)(HT - 1 - h)))
            * sqrtf(1.f + cs[b*C_N+src]) * sqrtf(1.f + cs[b*C_N+dst]);
    int k = threadIdx.x;  // 128
    atomicAdd(&Eg[((size_t)b * C_N + src) * DIMN + k], w * Y[(size_t)dst * DIMN + k]);
}

// ---------------- fused prologue: weight transpose + emb->bf16 + colsum + temp ----------------
// each TEnt: nm matrices of (K,N) f32 -> (nm*N, K) bf16
struct TEnt { const float* s; bf16* d; int K; int N; int nm; int tiles; };
struct PrepArgs {
    TEnt e[6];                       // 1840 tiles total
    const float* emb; bf16* embbf;   // 250 blocks
    const int* hist; float* colsum;  // 32 blocks
    float* temp;                     // 64 blocks
};

__global__ void k_prep(PrepArgs p) {
    int id = blockIdx.x;
    int t = threadIdx.y * 32 + threadIdx.x;
    if (id < 1840) {                 // ---- weight transpose tiles ----
        __shared__ float tl[32][33];
        TEnt en = p.e[0];
        #pragma unroll
        for (int k = 0; k < 6; ++k) {
            if (id < p.e[k].tiles) { en = p.e[k]; break; }
            id -= p.e[k].tiles;
        }
        int tn = en.N >> 5;
        int per = (en.K >> 5) * tn;
        int mat = id / per, t2 = id % per;
        int ty = t2 / tn, tx = t2 % tn;
        const float* s = en.s + (size_t)mat * en.K * en.N;
        bf16* d = en.d + (size_t)mat * en.N * en.K;
        int k0 = ty * 32, n0 = tx * 32;
        #pragma unroll
        for (int j = 0; j < 32; j += 8)
            tl[threadIdx.y + j][threadIdx.x] = s[(size_t)(k0 + threadIdx.y + j) * en.N + n0 + threadIdx.x];
        __syncthreads();
        #pragma unroll
        for (int j = 0; j < 32; j += 8)
            d[(size_t)(n0 + threadIdx.y + j) * en.K + k0 + threadIdx.x] = (bf16)tl[threadIdx.x][threadIdx.y + j];
        return;
    }
    id -= 1840;
    if (id < 250) {                  // ---- emb -> bf16 ----
        int i = (id * 256 + t) * 4;
        float4 v = *(const float4*)(p.emb + i);
        bf16* d = p.embbf;
        d[i] = (bf16)v.x; d[i+1] = (bf16)v.y; d[i+2] = (bf16)v.z; d[i+3] = (bf16)v.w;
        return;
    }
    id -= 250;
    if (id < 32) {                   // ---- colsum ----
        int e = id * 256 + t;
        if (e >= NEDGE) return;
        int s = e % (S_N-1); int bh = e / (S_N-1); int h = bh % HT; int b = bh / HT;
        const int* row = p.hist + (size_t)bh * S_N;
        int src = row[s], dst = row[s+1];
        if (src != C_N && dst != C_N && src != dst) {
            float w = 1.f + expf(-0.01f * (float)(HT - 1 - h));
            atomicAdd(&p.colsum[b * C_N + dst], w);
        }
        return;
    }
    id -= 32;
    {                                // ---- temporal table ----
        int s = id; int d = t;
        int k = d >> 1;
        float den = powf(10000.f, (2.f * (float)k) / 256.f);
        float arg = (float)s / den;
        p.temp[s * DM + d] = (d & 1) ? cosf(arg) : sinf(arg);
    }
}

// ---------------- bf16 MFMA GEMM (dbuf + prefetch) ----------------
// C[M,N] = epi(A[M,K] @ Bt[N,K]^T), EPI bits: 1=bias, 2=relu, 4=resid(f32,ldc),
// 8=bf16 out, 16=col-mask(col<nreal). Requires M%128==0, N%64==0, K%64==0.
template<int EPI>
__global__ __launch_bounds__(256) void k_bgemm(
        const bf16* __restrict__ A, const bf16* __restrict__ Bt,
        const float* __restrict__ bias, const float* __restrict__ resid,
        void* __restrict__ Cout, int M, int N, int K, int ldc, int nreal)
{
    __shared__ bf16 As[2][128 * 64];
    __shared__ bf16 Bs[2][64 * 64];
    int tid = threadIdx.x;
    int wid = tid >> 6, lane = tid & 63;
    int m0 = blockIdx.y * 128, n0 = blockIdx.x * 64;
    int wr = wid >> 1, wc = wid & 1;        // wave sub-tile: 64 rows x 32 cols
    int lr = lane >> 3, lc = lane & 7;
    int gc = lc ^ lr;                       // pre-swizzled global chunk (16B units)
    f32x4 acc[4][2] = {};
    int nkt = K >> 6;

#define STAGE_BG(kt, buf) { \
    int kb = (kt) << 6; \
    _Pragma("unroll") \
    for (int s = 0; s < 4; ++s) { \
        int seg = wid * 4 + s; int row = seg * 8 + lr; \
        GLOAD_LDS16(A + (size_t)(m0 + row) * K + kb + gc * 8, &As[buf][seg * 512]); \
    } \
    _Pragma("unroll") \
    for (int s = 0; s < 2; ++s) { \
        int seg = wid * 2 + s; int row = seg * 8 + lr; \
        GLOAD_LDS16(Bt + (size_t)(n0 + row) * K + kb + gc * 8, &Bs[buf][seg * 512]); \
    } }

    STAGE_BG(0, 0);
    __syncthreads();
    int cur = 0;
    for (int kt = 0; kt < nkt; ++kt) {
        if (kt + 1 < nkt) STAGE_BG(kt + 1, cur ^ 1);   // async prefetch, in flight during MFMA
        #pragma unroll
        for (int kk = 0; kk < 2; ++kk) {
            bf16x8 af[4], bfr[2];
            int c = kk * 4 + (lane >> 4);
            #pragma unroll
            for (int m = 0; m < 4; ++m) {
                int row = wr * 64 + m * 16 + (lane & 15);
                af[m] = *(const bf16x8*)(&As[cur][row * 64 + (c ^ (row & 7)) * 8]);
            }
            #pragma unroll
            for (int n = 0; n < 2; ++n) {
                int row = wc * 32 + n * 16 + (lane & 15);
                bfr[n] = *(const bf16x8*)(&Bs[cur][row * 64 + (c ^ (row & 7)) * 8]);
            }
            #pragma unroll
            for (int m = 0; m < 4; ++m)
                #pragma unroll
                for (int n = 0; n < 2; ++n)
                    acc[m][n] = __builtin_amdgcn_mfma_f32_16x16x32_bf16(af[m], bfr[n], acc[m][n], 0, 0, 0);
        }
        __syncthreads();    // drains prefetch vmcnt + LDS reads, one barrier per K-step
        cur ^= 1;
    }
#undef STAGE_BG
    int cl = lane & 15, ch = lane >> 4;
    #pragma unroll
    for (int n = 0; n < 2; ++n) {
        int col = n0 + wc * 32 + n * 16 + cl;
        if ((EPI & 16) && col >= nreal) continue;
        float bv = (EPI & 1) ? bias[col] : 0.f;
        #pragma unroll
        for (int m = 0; m < 4; ++m) {
            #pragma unroll
            for (int j = 0; j < 4; ++j) {
                int row = m0 + wr * 64 + m * 16 + ch * 4 + j;
                float v = acc[m][n][j] + bv;
                if (EPI & 4) v += resid[(size_t)row * ldc + col];
                if (EPI & 2) v = fmaxf(v, 0.f);
                if (EPI & 8) ((bf16*)Cout)[(size_t)row * ldc + col] = (bf16)v;
                else         ((float*)Cout)[(size_t)row * ldc + col] = v;
            }
        }
    }
}

// ---------------- bf16 MFMA GEMM + residual + LayerNorm fused (BM=32, dbuf) ----------------
// Xf (f32, [M,256]): resid in, LN result out (in place). Xb: bf16 copy out.
// tile: BM=32 x N=256 (full row), BK=64, 256 threads (4 waves, one col-quarter each).
// grid = M/32 blocks (272 for M=8704) -> all CUs covered.
__global__ __launch_bounds__(256) void k_bgemm_ln(
        const bf16* __restrict__ A, const bf16* __restrict__ Bt,
        const float* __restrict__ bias, float* __restrict__ Xf,
        const float* __restrict__ lns_, const float* __restrict__ lnb_,
        bf16* __restrict__ Xb, int M, int K)
{
    __shared__ bf16 As[2][32 * 64];
    __shared__ bf16 Bs[2][256 * 64];
    __shared__ float ls1[32][4], ls2[32][4];
    int tid = threadIdx.x, wid = tid >> 6, lane = tid & 63;
    int lr = lane >> 3, lc = lane & 7, gc = lc ^ lr;
    int cl = lane & 15, ch = lane >> 4;
    int m0 = blockIdx.x * 32;
    int wc = wid;                           // col quarter 0..3
    f32x4 acc[2][4] = {};
    int nkt = K >> 6;

#define STAGE_LN(kt, buf) { \
    int kb = (kt) << 6; \
    { int row = wid * 8 + lr; \
      GLOAD_LDS16(A + (size_t)(m0 + row) * K + kb + gc * 8, &As[buf][wid * 512]); } \
    _Pragma("unroll") \
    for (int s = 0; s < 8; ++s) { \
        int seg = wid * 8 + s; int row = seg * 8 + lr; \
        GLOAD_LDS16(Bt + (size_t)row * K + kb + gc * 8, &Bs[buf][seg * 512]); \
    } }

    STAGE_LN(0, 0);
    __syncthreads();
    int cur = 0;
    for (int kt = 0; kt < nkt; ++kt) {
        if (kt + 1 < nkt) STAGE_LN(kt + 1, cur ^ 1);
        #pragma unroll
        for (int kk = 0; kk < 2; ++kk) {
            int c = kk * 4 + ch;
            bf16x8 af[2], bfr[4];
            #pragma unroll
            for (int m = 0; m < 2; ++m) {
                int row = m * 16 + cl;
                af[m] = *(const bf16x8*)(&As[cur][row * 64 + (c ^ (row & 7)) * 8]);
            }
            #pragma unroll
            for (int n = 0; n < 4; ++n) {
                int row = wc * 64 + n * 16 + cl;
                bfr[n] = *(const bf16x8*)(&Bs[cur][row * 64 + (c ^ (row & 7)) * 8]);
            }
            #pragma unroll
            for (int m = 0; m < 2; ++m)
                #pragma unroll
                for (int n = 0; n < 4; ++n)
                    acc[m][n] = __builtin_amdgcn_mfma_f32_16x16x32_bf16(af[m], bfr[n], acc[m][n], 0, 0, 0);
        }
        __syncthreads();
        cur ^= 1;
    }
#undef STAGE_LN
    // pass 1: v = acc + bias + resid; row partial sums
    #pragma unroll
    for (int m = 0; m < 2; ++m) {
        #pragma unroll
        for (int j = 0; j < 4; ++j) {
            int rl = m * 16 + ch * 4 + j;
            float s1 = 0.f, s2 = 0.f;
            #pragma unroll
            for (int n = 0; n < 4; ++n) {
                int col = wc * 64 + n * 16 + cl;
                float v = acc[m][n][j] + bias[col] + Xf[(size_t)(m0 + rl) * 256 + col];
                acc[m][n][j] = v;
                s1 += v; s2 += v * v;
            }
            s1 += __shfl_xor(s1, 1); s2 += __shfl_xor(s2, 1);
            s1 += __shfl_xor(s1, 2); s2 += __shfl_xor(s2, 2);
            s1 += __shfl_xor(s1, 4); s2 += __shfl_xor(s2, 4);
            s1 += __shfl_xor(s1, 8); s2 += __shfl_xor(s2, 8);
            if (cl == 0) { ls1[rl][wc] = s1; ls2[rl][wc] = s2; }
        }
    }
    __syncthreads();
    // pass 2: normalize + write
    #pragma unroll
    for (int m = 0; m < 2; ++m) {
        #pragma unroll
        for (int j = 0; j < 4; ++j) {
            int rl = m * 16 + ch * 4 + j;
            float su = ls1[rl][0] + ls1[rl][1] + ls1[rl][2] + ls1[rl][3];
            float sq = ls2[rl][0] + ls2[rl][1] + ls2[rl][2] + ls2[rl][3];
            float mean = su * (1.f / 256.f);
            float var  = sq * (1.f / 256.f) - mean * mean;
            float rstd = rsqrtf(var + 1e-5f);
            #pragma unroll
            for (int n = 0; n < 4; ++n) {
                int col = wc * 64 + n * 16 + cl;
                float r = (acc[m][n][j] - mean) * rstd * lns_[col] + lnb_[col];
                size_t g = (size_t)(m0 + rl) * 256 + col;
                Xf[g] = r;
                Xb[g] = (bf16)r;
            }
        }
    }
}

// ---------------- fuse ----------------

__global__ void k_fuse(const int* __restrict__ hist, const int* __restrict__ cur,
                       const float* __restrict__ E, const float* __restrict__ Eg,
                       const float* __restrict__ nullE, const float* __restrict__ temp,
                       float* __restrict__ Xenc, bf16* __restrict__ Xbf,
                       float* __restrict__ maskb) {
    int blk = blockIdx.x;           // seq*64 + s
    int seq = blk >> 6, s = blk & 63;
    int d = threadIdx.x;
    int idx, b;
    if (seq < 128) { b = seq >> 4; idx = hist[(size_t)seq * S_N + s]; }
    else           { b = seq - 128; idx = cur[b * S_N + s]; }
    float t = temp[s * DM + d];
    float v;
    if (idx == C_N) v = nullE[d] + t;
    else {
        v = ((d < DIMN) ? E[(size_t)idx * DIMN + d]
                        : fmaxf(Eg[((size_t)b * C_N + idx) * DIMN + (d - DIMN)], 0.f)) + t;
    }
    size_t o = ((size_t)seq * S_N + s) * DM + d;
    Xenc[o] = v;
    Xbf[o]  = (bf16)v;
    if (d == 0) maskb[seq * S_N + s] = (idx == C_N) ? -INFINITY : 0.f;
}

// ---------------- MFMA attention: one wave per (seq, head) ----------------
template<bool WCA>
__global__ __launch_bounds__(64) void k_mattn(
        const bf16* __restrict__ Qb, const bf16* __restrict__ Kb,
        const bf16* __restrict__ Vb, const float* __restrict__ maskb,
        bf16* __restrict__ O, int qstr, int kstr)
{
    int seq = blockIdx.x >> 2, head = blockIdx.x & 3;
    int lane = threadIdx.x;
    int cl = lane & 15, ch = lane >> 4;
    __shared__ __align__(16) short VT[64 * 72];   // V^T [d][k]
    __shared__ __align__(16) short PT[64 * 72];   // P [q][k]; later O staging

    const bf16* Qp = Qb + (size_t)seq * 64 * qstr + head * 64;
    int kvseq = WCA ? (seq >> 4) : seq;
    const bf16* Kp = Kb + (size_t)kvseq * 64 * kstr + head * 64;
    const bf16* Vp = Vb + (size_t)kvseq * 64 * kstr + head * 64;

    bf16x8 aq[4][2], bk[4][2], vr[4][2];
    #pragma unroll
    for (int t = 0; t < 4; ++t)
        #pragma unroll
        for (int kk = 0; kk < 2; ++kk) {
            int row = t * 16 + cl, d0 = kk * 32 + ch * 8;
            aq[t][kk] = *(const bf16x8*)(Qp + (size_t)row * qstr + d0);
            bk[t][kk] = *(const bf16x8*)(Kp + (size_t)row * kstr + d0);
            vr[t][kk] = *(const bf16x8*)(Vp + (size_t)row * kstr + d0);
        }

    f32x4 sa[4][4] = {};
    #pragma unroll
    for (int kk = 0; kk < 2; ++kk)
        #pragma unroll
        for (int m = 0; m < 4; ++m)
            #pragma unroll
            for (int n = 0; n < 4; ++n)
                sa[m][n] = __builtin_amdgcn_mfma_f32_16x16x32_bf16(aq[m][kk], bk[n][kk], sa[m][n], 0, 0, 0);

    #pragma unroll
    for (int t = 0; t < 4; ++t)
        #pragma unroll
        for (int kk = 0; kk < 2; ++kk) {
            int k = t * 16 + cl, d0 = kk * 32 + ch * 8;
            #pragma unroll
            for (int e = 0; e < 8; ++e)
                VT[(d0 + e) * 72 + k] = vr[t][kk][e];
        }

    float mk4[4];
    if (!WCA) {
        #pragma unroll
        for (int n = 0; n < 4; ++n) mk4[n] = maskb[seq * 64 + n * 16 + cl];
    }

    #pragma unroll
    for (int m = 0; m < 4; ++m) {
        #pragma unroll
        for (int j = 0; j < 4; ++j) {
            int q = m * 16 + ch * 4 + j;
            float rm = -INFINITY;
            #pragma unroll
            for (int n = 0; n < 4; ++n) {
                int k = n * 16 + cl;
                float msk = WCA ? ((abs(q - k) <= 4) ? 0.f : -INFINITY) : mk4[n];
                float v = sa[m][n][j] * 0.125f + msk;
                sa[m][n][j] = v;
                rm = fmaxf(rm, v);
            }
            rm = fmaxf(rm, __shfl_xor(rm, 1));
            rm = fmaxf(rm, __shfl_xor(rm, 2));
            rm = fmaxf(rm, __shfl_xor(rm, 4));
            rm = fmaxf(rm, __shfl_xor(rm, 8));
            float rs = 0.f;
            #pragma unroll
            for (int n = 0; n < 4; ++n) {
                float e = expf(sa[m][n][j] - rm);
                sa[m][n][j] = e;
                rs += e;
            }
            rs += __shfl_xor(rs, 1);
            rs += __shfl_xor(rs, 2);
            rs += __shfl_xor(rs, 4);
            rs += __shfl_xor(rs, 8);
            float inv = 1.f / rs;
            #pragma unroll
            for (int n = 0; n < 4; ++n)
                PT[q * 72 + n * 16 + cl] = f2bf(sa[m][n][j] * inv);
        }
    }
    __syncthreads();

    f32x4 oa[4][4] = {};
    #pragma unroll
    for (int kk = 0; kk < 2; ++kk) {
        bf16x8 av[4], bp[4];
        #pragma unroll
        for (int dm = 0; dm < 4; ++dm)
            av[dm] = *(const bf16x8*)(VT + (dm * 16 + cl) * 72 + kk * 32 + ch * 8);
        #pragma unroll
        for (int qn = 0; qn < 4; ++qn)
            bp[qn] = *(const bf16x8*)(PT + (qn * 16 + cl) * 72 + kk * 32 + ch * 8);
        #pragma unroll
        for (int dm = 0; dm < 4; ++dm)
            #pragma unroll
            for (int qn = 0; qn < 4; ++qn)
                oa[dm][qn] = __builtin_amdgcn_mfma_f32_16x16x32_bf16(av[dm], bp[qn], oa[dm][qn], 0, 0, 0);
    }
    __syncthreads();

    #pragma unroll
    for (int dm = 0; dm < 4; ++dm)
        #pragma unroll
        for (int qn = 0; qn < 4; ++qn)
            #pragma unroll
            for (int j = 0; j < 4; ++j)
                PT[(qn * 16 + cl) * 72 + dm * 16 + ch * 4 + j] = f2bf(oa[dm][qn][j]);
    __syncthreads();
    #pragma unroll
    for (int it = 0; it < 8; ++it) {       // 512 chunks of 8 bf16
        int chunk = it * 64 + lane;
        int tok = chunk >> 3, d0 = (chunk & 7) * 8;
        bf16x8 v = *(const bf16x8*)(PT + tok * 72 + d0);
        *(bf16x8*)(O + ((size_t)seq * 64 + tok) * 256 + head * 64 + d0) = v;
    }
}

// ---------------- scores + softmax-over-h + aggregate (bf16 out) ----------------

__global__ __launch_bounds__(256) void k_agg(const float* __restrict__ wca,
                                             const float* __restrict__ mc,
                                             bf16* __restrict__ aggbf) {
    int bs = blockIdx.x; int b = bs >> 6, s = bs & 63;
    int d = threadIdx.x;
    __shared__ float red[4][16];
    float mcv = mc[((size_t)b * S_N + s) * DM + d];
    float wv[16], p[16];
    #pragma unroll
    for (int h = 0; h < 16; ++h) {
        wv[h] = wca[(((size_t)(b * HT + h)) * S_N + s) * DM + d];
        p[h] = wv[h] * mcv;
    }
    #pragma unroll
    for (int o = 1; o < 64; o <<= 1)
        #pragma unroll
        for (int h = 0; h < 16; ++h) p[h] += __shfl_xor(p[h], o);
    if ((d & 63) == 0) {
        int w = d >> 6;
        #pragma unroll
        for (int h = 0; h < 16; ++h) red[w][h] = p[h];
    }
    __syncthreads();
    float sc[16], mx = -INFINITY;
    #pragma unroll
    for (int h = 0; h < 16; ++h) {
        sc[h] = (red[0][h] + red[1][h] + red[2][h] + red[3][h]) * (1.f / 16.f);
        mx = fmaxf(mx, sc[h]);
    }
    float e[16], sum = 0.f;
    #pragma unroll
    for (int h = 0; h < 16; ++h) { e[h] = expf(sc[h] - mx); sum += e[h]; }
    float inv = 1.f / sum;
    float acc = 0.f;
    #pragma unroll
    for (int h = 0; h < 16; ++h) acc += e[h] * inv * wv[h];
    aggbf[((size_t)b * S_N + s) * DM + d] = (bf16)(acc + mcv);
}

// ---------------- launch ----------------

extern "C" void kernel_launch(void* const* d_in, const int* in_sizes, int n_in,
                              void* d_out, int out_size, void* d_ws, size_t ws_size,
                              hipStream_t stream) {
    const int*   history = (const int*)d_in[0];
    const int*   cur     = (const int*)d_in[1];
    const float* emb     = (const float*)d_in[2];
    const float* nullE   = (const float*)d_in[3];
    const float* gcn_w   = (const float*)d_in[4];
    const float* gcn_b   = (const float*)d_in[5];
    const float* aw      = (const float*)d_in[6];
    const float* ab      = (const float*)d_in[7];
    const float* fw1     = (const float*)d_in[8];
    const float* fb1     = (const float*)d_in[9];
    const float* fw2     = (const float*)d_in[10];
    const float* fb2     = (const float*)d_in[11];
    const float* lns     = (const float*)d_in[12];
    const float* lnb     = (const float*)d_in[13];
    const float* wca_w   = (const float*)d_in[14];
    const float* wca_b   = (const float*)d_in[15];
    const float* ial_w   = (const float*)d_in[16];
    const float* ial_b   = (const float*)d_in[17];
    float* out = (float*)d_out;
    float* ws  = (float*)d_ws;

    // ---- arena (float offsets) ----
    float* dvec   = ws + 0;            // 16,000  (colsum)
    float* maskb  = ws + 16000;        // 8,704
    float* temp   = ws + 24704;        // 16,384
    bf16*  aggbf  = (bf16*)(ws + 41088);         // 131,072 bf16 (512x256)
    bf16*  finalb = (bf16*)(ws + 106624);        // 65,536 bf16 (512x128)
    bf16*  embbf  = (bf16*)(ws + 139392);        // 262,144 bf16 (2048x128, padded)
    float* Y      = ws + 270464;       // 262,144 f32 (2048x128)
    float* Eg     = ws + 532608;       // 2,048,000 f32 (8x2000x128)
    bf16*  wbf    = (bf16*)(ws + 2580608);       // 1,884,160 bf16
    float* Xenc   = ws + 3522688;      // 2,228,224 f32
    bf16*  Xbf    = (bf16*)(ws + 5750912);       // 2,228,224 bf16
    bf16*  Abf    = (bf16*)(ws + 6865024);       // 2,228,224 bf16
    bf16*  Hbf    = (bf16*)(ws + 7979136);       // 8,912,896 bf16
    bf16*  QKVbf  = (bf16*)(ws + 12435584);      // 6,684,672 bf16
    float* SE     = ws + 15777920;     // 2,097,152 f32 (ends 17,875,072 f = 71.5 MiB)

    // bf16 weight sub-arena
    bf16* wbf_aw  = wbf;               // 8 x (256,256)
    bf16* wbf_fw1 = wbf + 524288;      // 2 x (1024,256)
    bf16* wbf_fw2 = wbf + 1048576;     // 2 x (256,1024)
    bf16* wbf_wca = wbf + 1572864;     // 4 x (256,256)
    bf16* wbf_gcn = wbf + 1835008;     // (128,128)
    bf16* wbf_ial = wbf + 1851392;     // (128,256)

    // aliases (QKV region reused for WCA)
    bf16* Qwbf = QKVbf;                // 8192x256
    bf16* KVbf = QKVbf + 4194304;      // 512x512

    // --- fused prologue ---
    hipMemsetAsync(dvec, 0, 16000 * sizeof(float), stream);
    hipMemsetAsync(embbf + 2000 * 128, 0, 48 * 128 * sizeof(bf16), stream);
    PrepArgs pa;
    pa.e[0] = { aw,    wbf_aw,  256,  256, 8, 512 };
    pa.e[1] = { fw1,   wbf_fw1, 256, 1024, 2, 512 };
    pa.e[2] = { fw2,   wbf_fw2, 1024, 256, 2, 512 };
    pa.e[3] = { wca_w, wbf_wca, 256,  256, 4, 256 };
    pa.e[4] = { gcn_w, wbf_gcn, 128,  128, 1,  16 };
    pa.e[5] = { ial_w, wbf_ial, 256,  128, 1,  32 };
    pa.emb = emb; pa.embbf = embbf;
    pa.hist = history; pa.colsum = dvec;
    pa.temp = temp;
    k_prep<<<1840 + 250 + 32 + 64, dim3(32, 8), 0, stream>>>(pa);

    // --- GCN:  A'(E@W) via Y = E@W then sparse scatter ---
    k_bgemm<0><<<dim3(2, 16), 256, 0, stream>>>(embbf, wbf_gcn, nullptr, nullptr, Y,
                                                2048, DIMN, DIMN, DIMN, DIMN);
    k_initX<<<B_N * C_N * DIMN / 256, 256, 0, stream>>>(dvec, Y, gcn_b, Eg);
    k_edgeX<<<NEDGE, 128, 0, stream>>>(history, dvec, Y, Eg);

    // --- fuse (relu(Eg) folded in) ---
    k_fuse<<<NSEQ * S_N, DM, 0, stream>>>(history, cur, emb, Eg, nullE, temp, Xenc, Xbf, maskb);

    // --- encoder, L=2 ---
    for (int l = 0; l < 2; ++l) {
        k_bgemm<9><<<dim3(12, 68), 256, 0, stream>>>(Xbf, wbf_aw + l * 262144,
                ab + l * 1024, nullptr, QKVbf, NSEQ * S_N, 768, 256, 768, 768);
        k_mattn<false><<<NSEQ * 4, 64, 0, stream>>>(QKVbf, QKVbf + 256, QKVbf + 512,
                maskb, Abf, 768, 768);
        k_bgemm_ln<<<272, 256, 0, stream>>>(Abf, wbf_aw + l * 262144 + 196608,
                ab + l * 1024 + 768, Xenc, lns + (l * 2 + 0) * DM, lnb + (l * 2 + 0) * DM,
                Xbf, NSEQ * S_N, 256);
        k_bgemm<11><<<dim3(16, 68), 256, 0, stream>>>(Xbf, wbf_fw1 + l * 262144,
                fb1 + l * DFF, nullptr, Hbf, NSEQ * S_N, DFF, 256, DFF, DFF);
        k_bgemm_ln<<<272, 256, 0, stream>>>(Hbf, wbf_fw2 + l * 262144,
                fb2 + l * DM, Xenc, lns + (l * 2 + 1) * DM, lnb + (l * 2 + 1) * DM,
                Xbf, NSEQ * S_N, 1024);
    }

    float* mh = Xenc;                            // 128 seqs f32
    bf16*  mc_bf = Xbf + (size_t)128 * S_N * DM; // 8 seqs bf16

    // --- windowed cross attention ---
    k_bgemm<9><<<dim3(4, 64), 256, 0, stream>>>(Xbf, wbf_wca, wca_b, nullptr, Qwbf,
                                                128 * S_N, 256, 256, 256, 256);
    k_bgemm<9><<<dim3(8, 4), 256, 0, stream>>>(mc_bf, wbf_wca + 65536, wca_b + 256, nullptr,
                                               KVbf, B_N * S_N, 512, 256, 512, 512);
    k_mattn<true><<<128 * 4, 64, 0, stream>>>(Qwbf, KVbf, KVbf + 256, nullptr, Abf, 256, 512);
    k_bgemm<5><<<dim3(4, 64), 256, 0, stream>>>(Abf, wbf_wca + 196608, wca_b + 768, mh, SE,
                                                128 * S_N, 256, 256, 256, 256);

    // --- aggregate + final (bf16 MFMA tail) ---
    k_agg<<<B_N * S_N, 256, 0, stream>>>(SE, Xenc + (size_t)128 * S_N * DM, aggbf);
    k_bgemm<11><<<dim3(2, 4), 256, 0, stream>>>(aggbf, wbf_ial, ial_b, nullptr, finalb,
                                                B_N * S_N, DIMN, DM, DIMN, DIMN);
    k_bgemm<16><<<dim3(32, 4), 256, 0, stream>>>(finalb, embbf, nullptr, nullptr, out,
                                                 B_N * S_N, 2048, DIMN, C_N, C_N);
}